// Round 12
// baseline (2248.508 us; speedup 1.0000x reference)
//
#include <hip/hip_runtime.h>
#include <hip/hip_bf16.h>
#include <stdint.h>

typedef __attribute__((ext_vector_type(8))) short short8;
typedef __attribute__((ext_vector_type(4))) float f32x4;

#define AS1 __attribute__((address_space(1)))
#define AS3 __attribute__((address_space(3)))

__device__ __forceinline__ short f2bf(float x) {
    __hip_bfloat16 h = __float2bfloat16(x);
    union { __hip_bfloat16 h; short s; } u; u.h = h; return u.s;
}

__device__ __forceinline__ void gload_lds16(const short* g, short* l) {
    __builtin_amdgcn_global_load_lds((const AS1 void*)g, (AS3 void*)l, 16, 0, 0);
}

#define SBAR()   __builtin_amdgcn_s_barrier()
#define WAITV(N) asm volatile("s_waitcnt vmcnt(" #N ")")
#define SCHED0() __builtin_amdgcn_sched_barrier(0)

// ---------------------------------------------------------------------------
// r12: B moved OFF the LDS port. r1-r11 plateaued at 45-47% MfmaUtil across
// five schedule variants; arithmetic shows why: per K-tile per CU the LDS
// port carried 192 KB reads + 64 KB staging writes ~ 2048-2800 cy ~ MFMA's
// 2484 cy -- two equal serialized resources. Now: A stays LDS-staged
// ([2buf][2kh][256][32], T2 chunk-XOR swizzle, 0 conflicts); B is loaded
// DIRECT global->register (wave reads 16 rows x 64B fully-consumed lines,
// L1-friendly, vmem port runs parallel to LDS). LDS traffic drops to
// ~160 KB ~ 1250 cy << MFMA. Two regions per K-tile (kk0/kk1), 2 barriers.
// B prefetch one region ahead: bC = kk0 frags, bN = kk1 frags (fixed roles,
// no dynamic reg indexing). Ledger (robust to in-region reorder):
//   R0 issues [bN(t)x4, StgA(t+1,h0)x2]; R1 issues [StgA(t+1,h1)x2, bC(t+1)x4].
//   R0 WAITV(6): retires StgA(t,h0) (8 outstanding -> 6).
//   R1 WAITV(6): retires StgA(t,h1)+bC(t) worst-case (compiler's own B-reg
//   waits usually retire them earlier). SBAR after each wait for cross-wave
//   LDS visibility; SCHED0 pins ds_reads below the confirmation.
// MODE: 0 = plain; 1 = QKVB (weight-prep: B col base += m0 & ~1023).
// TAPS==3: conv path; A rows remap through padded [2][8194][4096].
// ---------------------------------------------------------------------------
template<int TAPS, int MODE, bool F32OUT>
__global__ __launch_bounds__(512, 2) void gemm256(
    const short* __restrict__ A, int lda,
    const short* __restrict__ BT, int ldb, long long tapB,
    void* __restrict__ Cout, int ldc,
    const float* __restrict__ bias, int Ktiles)
{
    __shared__ __align__(16) short As[2 * 2 * 256 * 32];
    const int tid = threadIdx.x, lane = tid & 63, wid = tid >> 6;
    const int wm = wid >> 2, wn = wid & 3;
    const int m0 = blockIdx.y * 256, n0 = blockIdx.x * 256;
    const size_t arow0 = (TAPS == 3) ? ((size_t)(m0 >> 13) * 8194 + (size_t)(m0 & 8191))
                                     : (size_t)m0;
    const size_t ldaS = (size_t)lda, ldbS = (size_t)ldb, tapBS = (size_t)tapB;
    const short* Abase0 = A + arow0 * ldaS;
    const short* Bbase0 = BT + (size_t)n0 * ldbS + ((MODE == 1) ? (m0 & ~1023) : 0);
    const int c15 = lane & 15, g4 = (lane >> 4) * 4, g8 = (lane >> 4) * 8;
    const int swz = ((lane >> 4) ^ ((c15 >> 1) & 3)) * 8;
    const int srow = tid >> 2;
    const int schunk = (((tid & 3) ^ ((tid >> 3) & 3)) * 8);

#define STG_A(u, kh, buf) do { \
    const int tp_ = (TAPS == 3) ? ((u) >> 6) : 0; \
    const int kc_ = (TAPS == 3) ? (((u) & 63) << 6) : ((u) << 6); \
    const short* g_ = Abase0 + (size_t)tp_ * ldaS + kc_ + (kh) * 32 \
                      + (size_t)srow * ldaS + schunk; \
    short* l_ = As + (buf) * 16384 + (kh) * 8192 + wid * 512; \
    gload_lds16(g_, l_); \
    gload_lds16(g_ + 128 * ldaS, l_ + 4096); \
} while (0)

#define LDA_(buf, kk, mi) (*(const short8*)(As + (buf) * 16384 + (kk) * 8192 \
                           + (wm * 128 + (mi) * 16 + c15) * 32 + swz))

// direct global B fragment: row = n0+wn*64+nj*16+c15, cols kc+kk*32+g8..+8
#define BG(tt, kk, nj) (*(const short8*)(Bbase0 \
    + (size_t)((TAPS == 3) ? ((tt) >> 6) : 0) * tapBS \
    + (size_t)(wn * 64 + (nj) * 16 + c15) * ldbS \
    + ((TAPS == 3) ? (((tt) & 63) << 6) : ((tt) << 6)) + (kk) * 32 + g8))

#define MFMA4x4B(MB, B0, B1, B2, B3) do { \
    __builtin_amdgcn_s_setprio(1); \
    _Pragma("unroll") \
    for (int mi_ = 0; mi_ < 4; ++mi_) { \
        acc[(MB) + mi_][0] = __builtin_amdgcn_mfma_f32_16x16x32_bf16(af[mi_], B0, acc[(MB) + mi_][0], 0, 0, 0); \
        acc[(MB) + mi_][1] = __builtin_amdgcn_mfma_f32_16x16x32_bf16(af[mi_], B1, acc[(MB) + mi_][1], 0, 0, 0); \
        acc[(MB) + mi_][2] = __builtin_amdgcn_mfma_f32_16x16x32_bf16(af[mi_], B2, acc[(MB) + mi_][2], 0, 0, 0); \
        acc[(MB) + mi_][3] = __builtin_amdgcn_mfma_f32_16x16x32_bf16(af[mi_], B3, acc[(MB) + mi_][3], 0, 0, 0); \
    } \
    __builtin_amdgcn_s_setprio(0); \
} while (0)

    f32x4 acc[8][4];
    #pragma unroll
    for (int i = 0; i < 8; ++i)
        #pragma unroll
        for (int j = 0; j < 4; ++j)
            acc[i][j] = (f32x4){0.f, 0.f, 0.f, 0.f};

    short8 af[4];
    short8 bC0, bC1, bC2, bC3;   // kk=0 B frags (current tile)
    short8 bN0, bN1, bN2, bN3;   // kk=1 B frags

    // prologue: stage tile-0 A halves; load tile-0 kk0 B; drain once.
    STG_A(0, 0, 0); STG_A(0, 1, 0);
    bC0 = BG(0, 0, 0); bC1 = BG(0, 0, 1); bC2 = BG(0, 0, 2); bC3 = BG(0, 0, 3);
    WAITV(0); SBAR(); SCHED0();

    for (int t = 0; t < Ktiles; ++t) {
        const int c = t & 1, nb = c ^ 1;
        const bool st = (t + 1 < Ktiles);
        const int u = t + 1;

        // ---- region 0: kk=0 ----
        WAITV(6); SBAR(); SCHED0();            // confirms StgA(t,h0)
        #pragma unroll
        for (int mi = 0; mi < 4; ++mi) af[mi] = LDA_(c, 0, mi);
        bN0 = BG(t, 1, 0); bN1 = BG(t, 1, 1); bN2 = BG(t, 1, 2); bN3 = BG(t, 1, 3);
        if (st) STG_A(u, 0, nb);
        MFMA4x4B(0, bC0, bC1, bC2, bC3);
        #pragma unroll
        for (int mi = 0; mi < 4; ++mi) af[mi] = LDA_(c, 0, 4 + mi);
        MFMA4x4B(4, bC0, bC1, bC2, bC3);

        // ---- region 1: kk=1 ----
        WAITV(6); SBAR(); SCHED0();            // confirms StgA(t,h1) (+bC worst case)
        #pragma unroll
        for (int mi = 0; mi < 4; ++mi) af[mi] = LDA_(c, 1, mi);
        if (st) STG_A(u, 1, nb);
        if (st) { bC0 = BG(u, 0, 0); bC1 = BG(u, 0, 1); bC2 = BG(u, 0, 2); bC3 = BG(u, 0, 3); }
        MFMA4x4B(0, bN0, bN1, bN2, bN3);
        #pragma unroll
        for (int mi = 0; mi < 4; ++mi) af[mi] = LDA_(c, 1, 4 + mi);
        MFMA4x4B(4, bN0, bN1, bN2, bN3);
    }

    float bv[4];
    #pragma unroll
    for (int nj = 0; nj < 4; ++nj)
        bv[nj] = bias ? bias[n0 + wn * 64 + nj * 16 + c15] : 0.f;
    #pragma unroll
    for (int mi = 0; mi < 8; ++mi) {
        #pragma unroll
        for (int r = 0; r < 4; ++r) {
            const size_t row = (size_t)m0 + wm * 128 + mi * 16 + g4 + r;
            #pragma unroll
            for (int nj = 0; nj < 4; ++nj) {
                const int col = n0 + wn * 64 + nj * 16 + c15;
                const float v = acc[mi][nj][r] + bv[nj];
                if (F32OUT) ((float*)Cout)[row * (size_t)ldc + col] = v;
                else        ((short*)Cout)[row * (size_t)ldc + col] = f2bf(v);
            }
        }
    }
#undef STG_A
#undef LDA_
#undef BG
#undef MFMA4x4B
}

// ---------------------------------------------------------------------------
// Per (head, block) causal attention. qkvh: [16384][3072] bf16, q at cols
// 0-1023, k at +1024, v at +2048 (col within each = h*64+e). obuf [16384][1024].
// ---------------------------------------------------------------------------
__global__ __launch_bounds__(256) void attn_kernel(
    const short* __restrict__ qkvh, short* __restrict__ obuf)
{
    __shared__ __align__(16) char smem[54272];
    short* qs = (short*)smem;                 // [128][72]
    short* ks = (short*)smem + 9216;          // [128][72]
    short* vt = (short*)(smem + 36864);       // [64][136]  (v transposed)
    short* ps = (short*)smem;                 // [128][136] (reuses qs+ks region)
    short* os = (short*)smem;                 // [128][72]  (reused post-PV)

    const int tid = threadIdx.x, lane = tid & 63, wid = tid >> 6;
    const int h = blockIdx.x, b = blockIdx.y;
    const size_t base = (size_t)b * 128 * 3072 + (size_t)h * 64;

    for (int i = tid; i < 1024; i += 256) {
        const int row = i >> 3, c8 = i & 7;
        const size_t g = base + (size_t)row * 3072 + c8 * 8;
        *(short8*)(qs + row * 72 + c8 * 8) = *(const short8*)(qkvh + g);
        *(short8*)(ks + row * 72 + c8 * 8) = *(const short8*)(qkvh + g + 1024);
        short8 vv = *(const short8*)(qkvh + g + 2048);
        #pragma unroll
        for (int j = 0; j < 8; ++j) vt[(c8 * 8 + j) * 136 + row] = vv[j];
    }
    __syncthreads();

    const int c15 = lane & 15, g8 = (lane >> 4) * 8, g4 = (lane >> 4) * 4;
    const int r0 = wid * 32;

    f32x4 sacc[2][8];
    #pragma unroll
    for (int mi = 0; mi < 2; ++mi)
        #pragma unroll
        for (int nj = 0; nj < 8; ++nj)
            sacc[mi][nj] = (f32x4){0.f, 0.f, 0.f, 0.f};
    #pragma unroll
    for (int kk = 0; kk < 2; ++kk) {
        short8 aq[2];
        #pragma unroll
        for (int mi = 0; mi < 2; ++mi)
            aq[mi] = *(const short8*)(qs + (r0 + mi * 16 + c15) * 72 + kk * 32 + g8);
        #pragma unroll
        for (int nj = 0; nj < 8; ++nj) {
            short8 bk8 = *(const short8*)(ks + (nj * 16 + c15) * 72 + kk * 32 + g8);
            #pragma unroll
            for (int mi = 0; mi < 2; ++mi)
                sacc[mi][nj] = __builtin_amdgcn_mfma_f32_16x16x32_bf16(
                    aq[mi], bk8, sacc[mi][nj], 0, 0, 0);
        }
    }
    __syncthreads();

    #pragma unroll
    for (int mi = 0; mi < 2; ++mi) {
        #pragma unroll
        for (int r = 0; r < 4; ++r) {
            const int qrow = r0 + mi * 16 + g4 + r;
            float m = -3.0e38f, pv[8];
            #pragma unroll
            for (int nj = 0; nj < 8; ++nj) {
                float s = sacc[mi][nj][r] * 0.125f;
                if (nj * 16 + c15 > qrow) s = -1.0e9f;
                pv[nj] = s; m = fmaxf(m, s);
            }
            #pragma unroll
            for (int off = 8; off >= 1; off >>= 1) m = fmaxf(m, __shfl_xor(m, off));
            float sum = 0.f;
            #pragma unroll
            for (int nj = 0; nj < 8; ++nj) { float p = __expf(pv[nj] - m); pv[nj] = p; sum += p; }
            #pragma unroll
            for (int off = 8; off >= 1; off >>= 1) sum += __shfl_xor(sum, off);
            const float inv = 1.0f / sum;
            #pragma unroll
            for (int nj = 0; nj < 8; ++nj)
                ps[qrow * 136 + nj * 16 + c15] = f2bf(pv[nj] * inv);
        }
    }
    __syncthreads();

    f32x4 oacc[2][4];
    #pragma unroll
    for (int mi = 0; mi < 2; ++mi)
        #pragma unroll
        for (int nj = 0; nj < 4; ++nj)
            oacc[mi][nj] = (f32x4){0.f, 0.f, 0.f, 0.f};
    #pragma unroll
    for (int kt = 0; kt < 4; ++kt) {
        short8 ap[2];
        #pragma unroll
        for (int mi = 0; mi < 2; ++mi)
            ap[mi] = *(const short8*)(ps + (r0 + mi * 16 + c15) * 136 + kt * 32 + g8);
        #pragma unroll
        for (int nj = 0; nj < 4; ++nj) {
            short8 bv8 = *(const short8*)(vt + (nj * 16 + c15) * 136 + kt * 32 + g8);
            #pragma unroll
            for (int mi = 0; mi < 2; ++mi)
                oacc[mi][nj] = __builtin_amdgcn_mfma_f32_16x16x32_bf16(
                    ap[mi], bv8, oacc[mi][nj], 0, 0, 0);
        }
    }
    __syncthreads();

    #pragma unroll
    for (int mi = 0; mi < 2; ++mi)
        #pragma unroll
        for (int r = 0; r < 4; ++r)
            #pragma unroll
            for (int nj = 0; nj < 4; ++nj)
                os[(r0 + mi * 16 + g4 + r) * 72 + nj * 16 + c15] = f2bf(oacc[mi][nj][r]);
    __syncthreads();

    for (int i = tid; i < 1024; i += 256) {
        const int row = i >> 3, c8 = i & 7;
        *(short8*)(obuf + (size_t)b * 128 * 1024 + (size_t)h * 64
                   + (size_t)row * 1024 + c8 * 8) =
            *(const short8*)(os + row * 72 + c8 * 8);
    }
}

// ---------------------------------------------------------------------------
__global__ void pad_convert_inputs(const float* __restrict__ in, short* __restrict__ out)
{
    const int row = blockIdx.x;                 // [0, 16388)
    const int n = row / 8194, l = row % 8194;
    short* orow = out + (size_t)row * 4096;
    if (l == 0 || l == 8193) {
        for (int i = threadIdx.x; i < 512; i += 256) {
            uint4 z; z.x = z.y = z.z = z.w = 0u;
            *(uint4*)(orow + i * 8) = z;
        }
    } else {
        const float* irow = in + ((size_t)n * 8192 + (l - 1)) * 4096;
        for (int i = threadIdx.x; i < 512; i += 256) {
            float4 a = *(const float4*)(irow + i * 8);
            float4 b = *(const float4*)(irow + i * 8 + 4);
            short8 v;
            v[0] = f2bf(a.x); v[1] = f2bf(a.y); v[2] = f2bf(a.z); v[3] = f2bf(a.w);
            v[4] = f2bf(b.x); v[5] = f2bf(b.y); v[6] = f2bf(b.z); v[7] = f2bf(b.w);
            *(short8*)(orow + i * 8) = v;
        }
    }
}

__global__ void transpose_convert(const float* __restrict__ in, short* __restrict__ out,
                                  int R, int C)
{
    __shared__ float tile[32][33];
    const int tx = threadIdx.x & 31, ty = threadIdx.x >> 5;   // 32 x 8
    const int bx = blockIdx.x * 32, by = blockIdx.y * 32;
    #pragma unroll
    for (int i = 0; i < 32; i += 8)
        tile[ty + i][tx] = in[(size_t)(by + ty + i) * C + bx + tx];
    __syncthreads();
    #pragma unroll
    for (int i = 0; i < 32; i += 8)
        out[(size_t)(bx + ty + i) * R + by + tx] = f2bf(tile[tx][ty + i]);
}

__global__ void convert_bf16(const float* __restrict__ in, short* __restrict__ out, int n8)
{
    const int idx = blockIdx.x * 256 + threadIdx.x;
    if (idx < n8) {
        float4 a = *(const float4*)(in + (size_t)idx * 8);
        float4 b = *(const float4*)(in + (size_t)idx * 8 + 4);
        short8 v;
        v[0] = f2bf(a.x); v[1] = f2bf(a.y); v[2] = f2bf(a.z); v[3] = f2bf(a.w);
        v[4] = f2bf(b.x); v[5] = f2bf(b.y); v[6] = f2bf(b.z); v[7] = f2bf(b.w);
        *(short8*)(out + (size_t)idx * 8) = v;
    }
}

__global__ void fuse_bias(const float* __restrict__ bo, const float* __restrict__ projw,
                          const float* __restrict__ projb, float* __restrict__ outb)
{
    const int j = blockIdx.x * 256 + threadIdx.x;   // 4096
    float s = projb[j];
    for (int w = 0; w < 1024; ++w) s = fmaf(bo[w], projw[(size_t)w * 4096 + j], s);
    outb[j] = s;
}

// b2[o] = b_part[o&1023] + sum_d conv_b[(o>>10)*1024+d] * wpart[d][o&1023]
__global__ void fuse_bias_qkv(const float* __restrict__ conv_b,
                              const float* __restrict__ wq, const float* __restrict__ bq,
                              const float* __restrict__ wk, const float* __restrict__ bk,
                              const float* __restrict__ wv, const float* __restrict__ bv,
                              float* __restrict__ outb)
{
    const int o = blockIdx.x * 256 + threadIdx.x;   // 3072
    const int p = o >> 10, e = o & 1023;
    const float* w = (p == 0) ? wq : (p == 1) ? wk : wv;
    const float* bb = (p == 0) ? bq : (p == 1) ? bk : bv;
    const float* cb = conv_b + p * 1024;
    float s = bb[e];
    for (int d = 0; d < 1024; ++d) s = fmaf(cb[d], w[(size_t)d * 1024 + e], s);
    outb[o] = s;
}

// ---------------------------------------------------------------------------
extern "C" void kernel_launch(void* const* d_in, const int* in_sizes, int n_in,
                              void* d_out, int out_size, void* d_ws, size_t ws_size,
                              hipStream_t stream)
{
    const float* inputs = (const float*)d_in[0];
    const float* conv_w = (const float*)d_in[1];
    const float* conv_b = (const float*)d_in[2];
    const float* wq     = (const float*)d_in[3];
    const float* bq     = (const float*)d_in[4];
    const float* wk     = (const float*)d_in[5];
    const float* bk     = (const float*)d_in[6];
    const float* wv     = (const float*)d_in[7];
    const float* bv     = (const float*)d_in[8];
    const float* wo     = (const float*)d_in[9];
    const float* bo     = (const float*)d_in[10];
    const float* proj_w = (const float*)d_in[11];
    const float* proj_b = (const float*)d_in[12];

    char* ws = (char*)d_ws;
    short* in_pad = (short*)(ws + 0);             // [2][8194][4096]      134,283,264 B
    short* cw_bf  = (short*)(ws + 134283264);     // [3][4096][3072] bf16 (dead after prep)
    short* qkvh   = (short*)(ws + 134283264);     // [16384][3072] over cw_bf
    short* W2T    = (short*)(ws + 234946560);     // [3][3072][4096] bf16
    short* wq_t   = (short*)(ws + 310444032);     // [3][1024][1024] BT contiguous
    short* wo_bf  = (short*)(ws + 316735488);     // [1024][1024]
    short* proj_t = (short*)(ws + 318832640);     // [4096][1024]
    short* WfT    = (short*)(ws + 327221248);     // [4096][1024]
    float* bfused = (float*)(ws + 335609856);     // [4096]
    float* b2     = (float*)(ws + 335626240);     // [3072]
    short* o_buf  = (short*)(ws + 0);             // [16384][1024] over in_pad

    dim3 blk(256), blk5(512);

    pad_convert_inputs<<<16388, blk, 0, stream>>>(inputs, in_pad);
    convert_bf16<<<18432, blk, 0, stream>>>(conv_w, cw_bf, 4718592);   // straight convert
    transpose_convert<<<dim3(32, 32), blk, 0, stream>>>(wq, wq_t, 1024, 1024);
    transpose_convert<<<dim3(32, 32), blk, 0, stream>>>(wk, wq_t + 1048576, 1024, 1024);
    transpose_convert<<<dim3(32, 32), blk, 0, stream>>>(wv, wq_t + 2097152, 1024, 1024);
    transpose_convert<<<dim3(128, 32), blk, 0, stream>>>(proj_w, proj_t, 1024, 4096);
    convert_bf16<<<512, blk, 0, stream>>>(wo, wo_bf, 131072);
    fuse_bias<<<16, blk, 0, stream>>>(bo, proj_w, proj_b, bfused);
    fuse_bias_qkv<<<12, blk, 0, stream>>>(conv_b, wq, bq, wk, bk, wv, bv, b2);

    // WfT[dm][he] = sum_w proj_t[dm][w] * wo_flat[he][w]
    gemm256<1, 0, false><<<dim3(4, 16), blk5, 0, stream>>>(
        proj_t, 1024, wo_bf, 1024, 0, WfT, 1024, nullptr, 16);
    // weight prep: W2T[t][o][i] = sum_d wqkvT[o][d] * conv_w[t][i][(o>>10)*1024+d]
    for (int t = 0; t < 3; ++t)
        gemm256<1, 1, false><<<dim3(16, 12), blk5, 0, stream>>>(
            wq_t, 1024, cw_bf + (size_t)t * 4096 * 3072, 3072, 0,
            W2T + (size_t)t * 3072 * 4096, 4096, nullptr, 16);
    // fused conv+projection as 3-tap GEMM -> qkvh [16384][3072]
    gemm256<3, 0, false><<<dim3(12, 64), blk5, 0, stream>>>(
        in_pad, 4096, W2T, 4096, (long long)3072 * 4096, qkvh, 3072, b2, 192);

    attn_kernel<<<dim3(16, 128), blk, 0, stream>>>(qkvh, o_buf);

    // out = o @ Wf + bfused   (f32 out)
    gemm256<1, 0, true><<<dim3(16, 64), blk5, 0, stream>>>(
        o_buf, 1024, WfT, 1024, 0, d_out, 4096, bfused, 16);
}

// Round 13
// 1775.111 us; speedup vs baseline: 1.2667x; 1.2667x over previous
//
#include <hip/hip_runtime.h>
#include <hip/hip_bf16.h>
#include <stdint.h>

typedef __attribute__((ext_vector_type(8))) short short8;
typedef __attribute__((ext_vector_type(4))) float f32x4;
typedef __attribute__((ext_vector_type(16))) float f32x16;

#define AS1 __attribute__((address_space(1)))
#define AS3 __attribute__((address_space(3)))

__device__ __forceinline__ short f2bf(float x) {
    __hip_bfloat16 h = __float2bfloat16(x);
    union { __hip_bfloat16 h; short s; } u; u.h = h; return u.s;
}

__device__ __forceinline__ void gload_lds16(const short* g, short* l) {
    __builtin_amdgcn_global_load_lds((const AS1 void*)g, (AS3 void*)l, 16, 0, 0);
}

#define SBAR()   __builtin_amdgcn_s_barrier()
#define WAITV(N) asm volatile("s_waitcnt vmcnt(" #N ")")
#define SCHED0() __builtin_amdgcn_sched_barrier(0)

// ---------------------------------------------------------------------------
// r13: r11's schedule (best measured family member) ported to the 32x32x16
// MFMA pipe (ubench 2382 vs 2075 TF, +15% ceiling; FLOP/inst doubles; LDS
// read bytes per wave-tile IDENTICAL -- 24 b128/K-tile). 256x256 tile, BK=64,
// 8 waves (2M x 4N), per-wave out 128x64 = 4mi x 2nj tiles of 32x32.
// Phases (kh, mh): reads 8/4/8/4, 8 MFMA each (2mi x 2nj x 2ks, acc chain 2).
// Operand frags: row = lane&31, k = (lane>>5)*8+j for BOTH A and B (same
// k-mapping -> permutation cancels). C/D: col=lane&31,
// row=(r&3)+8*(r>>2)+4*(lane>>5) (m74/m101 HW-verified).
// LDS [2buf][2kh][256][32] + chunk-XOR swizzle slot^=(row>>1)&3: 8-lane
// group (rows 0-7, fixed chunk) spans all 32 banks -> conflict-free.
// Ledger (r5): prologue vmcnt(4) confirms t0.kh0; ph1 vmcnt(4) confirms
// t.kh1; ph3 vmcnt(4) confirms (t+1).kh0.
// MODE: 0 = plain; 1 = QKVB (weight-prep: B col base += m0 & ~1023).
// TAPS==3: conv path; A rows remap through padded [2][8194][4096].
// ---------------------------------------------------------------------------
template<int TAPS, int MODE, bool F32OUT>
__global__ __launch_bounds__(512, 2) void gemm256(
    const short* __restrict__ A, int lda,
    const short* __restrict__ BT, int ldb, long long tapB,
    void* __restrict__ Cout, int ldc,
    const float* __restrict__ bias, int Ktiles)
{
    __shared__ __align__(16) short As[2 * 2 * 256 * 32];
    __shared__ __align__(16) short Bs[2 * 2 * 256 * 32];
    const int tid = threadIdx.x, lane = tid & 63, wid = tid >> 6;
    const int wm = wid >> 2, wn = wid & 3;
    const int m0 = blockIdx.y * 256, n0 = blockIdx.x * 256;
    const size_t arow0 = (TAPS == 3) ? ((size_t)(m0 >> 13) * 8194 + (size_t)(m0 & 8191))
                                     : (size_t)m0;
    const size_t ldaS = (size_t)lda, ldbS = (size_t)ldb, tapBS = (size_t)tapB;
    const short* Abase0 = A + arow0 * ldaS;
    const short* Bbase0 = BT + (size_t)n0 * ldbS + ((MODE == 1) ? (m0 & ~1023) : 0);
    const int r31 = lane & 31, khl = lane >> 5;     // frag row / k-block half
    const int swzR = (r31 >> 1) & 3;                // row-based slot XOR
    const int srow = tid >> 2;
    const int schunk = (((tid & 3) ^ ((tid >> 3) & 3)) * 8);

#define STG_A(u, kh, buf) do { \
    const int tp_ = (TAPS == 3) ? ((u) >> 6) : 0; \
    const int kc_ = (TAPS == 3) ? (((u) & 63) << 6) : ((u) << 6); \
    const short* g_ = Abase0 + (size_t)tp_ * ldaS + kc_ + (kh) * 32 \
                      + (size_t)srow * ldaS + schunk; \
    short* l_ = As + (buf) * 16384 + (kh) * 8192 + wid * 512; \
    gload_lds16(g_, l_); \
    gload_lds16(g_ + 128 * ldaS, l_ + 4096); \
} while (0)

#define STG_B(u, kh, buf) do { \
    const int tp_ = (TAPS == 3) ? ((u) >> 6) : 0; \
    const int kc_ = (TAPS == 3) ? (((u) & 63) << 6) : ((u) << 6); \
    const short* g_ = Bbase0 + (size_t)tp_ * tapBS + kc_ + (kh) * 32 \
                      + (size_t)srow * ldbS + schunk; \
    short* l_ = Bs + (buf) * 16384 + (kh) * 8192 + wid * 512; \
    gload_lds16(g_, l_); \
    gload_lds16(g_ + 128 * ldbS, l_ + 4096); \
} while (0)

// frag read: 32-row block blk32, MFMA k-step ks (0..3); kh = ks>>1.
// chunk = (ks&1)*2 + khl, swizzled slot = chunk ^ ((row>>1)&3).
#define LDA32(buf, blk, ks) (*(const short8*)(As + (buf) * 16384 + ((ks) >> 1) * 8192 \
    + ((blk) * 32 + r31) * 32 + ((((ks) & 1) * 2 + khl) ^ swzR) * 8))
#define LDB32(buf, blk, ks) (*(const short8*)(Bs + (buf) * 16384 + ((ks) >> 1) * 8192 \
    + ((blk) * 32 + r31) * 32 + ((((ks) & 1) * 2 + khl) ^ swzR) * 8))

#define MM32(mi, nj, Av, Bv) acc[mi][nj] = \
    __builtin_amdgcn_mfma_f32_32x32x16_bf16(Av, Bv, acc[mi][nj], 0, 0, 0)

// 8 MFMA: mi in {MB, MB+1}, nj in {0,1}, 2 ks steps (chained per acc)
#define MFMA8(MB) do { \
    __builtin_amdgcn_s_setprio(1); \
    MM32((MB) + 0, 0, aK0m0, b0k0); MM32((MB) + 0, 1, aK0m0, b1k0); \
    MM32((MB) + 1, 0, aK0m1, b0k0); MM32((MB) + 1, 1, aK0m1, b1k0); \
    MM32((MB) + 0, 0, aK1m0, b0k1); MM32((MB) + 0, 1, aK1m0, b1k1); \
    MM32((MB) + 1, 0, aK1m1, b0k1); MM32((MB) + 1, 1, aK1m1, b1k1); \
    __builtin_amdgcn_s_setprio(0); \
} while (0)

    f32x16 acc[4][2];
    #pragma unroll
    for (int i = 0; i < 4; ++i)
        #pragma unroll
        for (int j = 0; j < 2; ++j)
            #pragma unroll
            for (int e = 0; e < 16; ++e)
                acc[i][j][e] = 0.f;

    // prologue: tile 0, issue order = Akh0, Bkh0, Akh1, Bkh1 (8 loads)
    STG_A(0, 0, 0); STG_B(0, 0, 0); STG_A(0, 1, 0); STG_B(0, 1, 0);
    WAITV(4); SBAR(); SCHED0();   // kh0 of tile 0 resident; kh1 in flight

    for (int t = 0; t < Ktiles; ++t) {
        const int c = t & 1, nb = c ^ 1;
        const bool st = (t + 1 < Ktiles);
        const int u = t + 1;
        const int bA = wm * 4, bB = wn * 2;
        short8 aK0m0, aK0m1, aK1m0, aK1m1, b0k0, b1k0, b0k1, b1k1;

        // ---- ph0: kh=0 (ks 0,1), mi 0-1 (+ B ks 0,1) ----
        aK0m0 = LDA32(c, bA + 0, 0); aK0m1 = LDA32(c, bA + 1, 0);
        aK1m0 = LDA32(c, bA + 0, 1); aK1m1 = LDA32(c, bA + 1, 1);
        b0k0 = LDB32(c, bB + 0, 0);  b1k0 = LDB32(c, bB + 1, 0);
        b0k1 = LDB32(c, bB + 0, 1);  b1k1 = LDB32(c, bB + 1, 1);
        if (st) STG_A(u, 0, nb);
        SBAR();
        MFMA8(0);
        SBAR();

        // ---- ph1: kh=0, mi 2-3 (reuse b); confirm kh1(t) ----
        aK0m0 = LDA32(c, bA + 2, 0); aK0m1 = LDA32(c, bA + 3, 0);
        aK1m0 = LDA32(c, bA + 2, 1); aK1m1 = LDA32(c, bA + 3, 1);
        if (st) STG_B(u, 0, nb);
        if (st) { WAITV(4); } else { WAITV(0); }
        SBAR(); SCHED0();
        MFMA8(2);
        SBAR();

        // ---- ph2: kh=1 (ks 2,3), mi 0-1 (+ B ks 2,3) ----
        aK0m0 = LDA32(c, bA + 0, 2); aK0m1 = LDA32(c, bA + 1, 2);
        aK1m0 = LDA32(c, bA + 0, 3); aK1m1 = LDA32(c, bA + 1, 3);
        b0k0 = LDB32(c, bB + 0, 2);  b1k0 = LDB32(c, bB + 1, 2);
        b0k1 = LDB32(c, bB + 0, 3);  b1k1 = LDB32(c, bB + 1, 3);
        if (st) STG_A(u, 1, nb);
        SBAR();
        MFMA8(0);
        SBAR();

        // ---- ph3: kh=1, mi 2-3 (reuse b); confirm kh0(t+1) ----
        aK0m0 = LDA32(c, bA + 2, 2); aK0m1 = LDA32(c, bA + 3, 2);
        aK1m0 = LDA32(c, bA + 2, 3); aK1m1 = LDA32(c, bA + 3, 3);
        if (st) STG_B(u, 1, nb);
        if (st) { WAITV(4); } else { WAITV(0); }
        SBAR(); SCHED0();
        MFMA8(2);
        SBAR();
    }

    // epilogue: C/D layout col=lane&31, row=(r&3)+8*(r>>2)+4*(lane>>5)
    float bv2[2];
    #pragma unroll
    for (int nj = 0; nj < 2; ++nj)
        bv2[nj] = bias ? bias[n0 + wn * 64 + nj * 32 + r31] : 0.f;
    #pragma unroll
    for (int mi = 0; mi < 4; ++mi) {
        #pragma unroll
        for (int r = 0; r < 16; ++r) {
            const size_t row = (size_t)m0 + wm * 128 + mi * 32
                               + (r & 3) + 8 * (r >> 2) + 4 * khl;
            #pragma unroll
            for (int nj = 0; nj < 2; ++nj) {
                const int col = n0 + wn * 64 + nj * 32 + r31;
                const float v = acc[mi][nj][r] + bv2[nj];
                if (F32OUT) ((float*)Cout)[row * (size_t)ldc + col] = v;
                else        ((short*)Cout)[row * (size_t)ldc + col] = f2bf(v);
            }
        }
    }
#undef STG_A
#undef STG_B
#undef LDA32
#undef LDB32
#undef MM32
#undef MFMA8
}

// ---------------------------------------------------------------------------
// Per (head, block) causal attention. qkvh: [16384][3072] bf16, q at cols
// 0-1023, k at +1024, v at +2048 (col within each = h*64+e). obuf [16384][1024].
// ---------------------------------------------------------------------------
__global__ __launch_bounds__(256) void attn_kernel(
    const short* __restrict__ qkvh, short* __restrict__ obuf)
{
    __shared__ __align__(16) char smem[54272];
    short* qs = (short*)smem;                 // [128][72]
    short* ks = (short*)smem + 9216;          // [128][72]
    short* vt = (short*)(smem + 36864);       // [64][136]  (v transposed)
    short* ps = (short*)smem;                 // [128][136] (reuses qs+ks region)
    short* os = (short*)smem;                 // [128][72]  (reused post-PV)

    const int tid = threadIdx.x, lane = tid & 63, wid = tid >> 6;
    const int h = blockIdx.x, b = blockIdx.y;
    const size_t base = (size_t)b * 128 * 3072 + (size_t)h * 64;

    for (int i = tid; i < 1024; i += 256) {
        const int row = i >> 3, c8 = i & 7;
        const size_t g = base + (size_t)row * 3072 + c8 * 8;
        *(short8*)(qs + row * 72 + c8 * 8) = *(const short8*)(qkvh + g);
        *(short8*)(ks + row * 72 + c8 * 8) = *(const short8*)(qkvh + g + 1024);
        short8 vv = *(const short8*)(qkvh + g + 2048);
        #pragma unroll
        for (int j = 0; j < 8; ++j) vt[(c8 * 8 + j) * 136 + row] = vv[j];
    }
    __syncthreads();

    const int c15 = lane & 15, g8 = (lane >> 4) * 8, g4 = (lane >> 4) * 4;
    const int r0 = wid * 32;

    f32x4 sacc[2][8];
    #pragma unroll
    for (int mi = 0; mi < 2; ++mi)
        #pragma unroll
        for (int nj = 0; nj < 8; ++nj)
            sacc[mi][nj] = (f32x4){0.f, 0.f, 0.f, 0.f};
    #pragma unroll
    for (int kk = 0; kk < 2; ++kk) {
        short8 aq[2];
        #pragma unroll
        for (int mi = 0; mi < 2; ++mi)
            aq[mi] = *(const short8*)(qs + (r0 + mi * 16 + c15) * 72 + kk * 32 + g8);
        #pragma unroll
        for (int nj = 0; nj < 8; ++nj) {
            short8 bk8 = *(const short8*)(ks + (nj * 16 + c15) * 72 + kk * 32 + g8);
            #pragma unroll
            for (int mi = 0; mi < 2; ++mi)
                sacc[mi][nj] = __builtin_amdgcn_mfma_f32_16x16x32_bf16(
                    aq[mi], bk8, sacc[mi][nj], 0, 0, 0);
        }
    }
    __syncthreads();

    #pragma unroll
    for (int mi = 0; mi < 2; ++mi) {
        #pragma unroll
        for (int r = 0; r < 4; ++r) {
            const int qrow = r0 + mi * 16 + g4 + r;
            float m = -3.0e38f, pv[8];
            #pragma unroll
            for (int nj = 0; nj < 8; ++nj) {
                float s = sacc[mi][nj][r] * 0.125f;
                if (nj * 16 + c15 > qrow) s = -1.0e9f;
                pv[nj] = s; m = fmaxf(m, s);
            }
            #pragma unroll
            for (int off = 8; off >= 1; off >>= 1) m = fmaxf(m, __shfl_xor(m, off));
            float sum = 0.f;
            #pragma unroll
            for (int nj = 0; nj < 8; ++nj) { float p = __expf(pv[nj] - m); pv[nj] = p; sum += p; }
            #pragma unroll
            for (int off = 8; off >= 1; off >>= 1) sum += __shfl_xor(sum, off);
            const float inv = 1.0f / sum;
            #pragma unroll
            for (int nj = 0; nj < 8; ++nj)
                ps[qrow * 136 + nj * 16 + c15] = f2bf(pv[nj] * inv);
        }
    }
    __syncthreads();

    f32x4 oacc[2][4];
    #pragma unroll
    for (int mi = 0; mi < 2; ++mi)
        #pragma unroll
        for (int nj = 0; nj < 4; ++nj)
            oacc[mi][nj] = (f32x4){0.f, 0.f, 0.f, 0.f};
    #pragma unroll
    for (int kt = 0; kt < 4; ++kt) {
        short8 ap[2];
        #pragma unroll
        for (int mi = 0; mi < 2; ++mi)
            ap[mi] = *(const short8*)(ps + (r0 + mi * 16 + c15) * 136 + kt * 32 + g8);
        #pragma unroll
        for (int nj = 0; nj < 4; ++nj) {
            short8 bv8 = *(const short8*)(vt + (nj * 16 + c15) * 136 + kt * 32 + g8);
            #pragma unroll
            for (int mi = 0; mi < 2; ++mi)
                oacc[mi][nj] = __builtin_amdgcn_mfma_f32_16x16x32_bf16(
                    ap[mi], bv8, oacc[mi][nj], 0, 0, 0);
        }
    }
    __syncthreads();

    #pragma unroll
    for (int mi = 0; mi < 2; ++mi)
        #pragma unroll
        for (int r = 0; r < 4; ++r)
            #pragma unroll
            for (int nj = 0; nj < 4; ++nj)
                os[(r0 + mi * 16 + g4 + r) * 72 + nj * 16 + c15] = f2bf(oacc[mi][nj][r]);
    __syncthreads();

    for (int i = tid; i < 1024; i += 256) {
        const int row = i >> 3, c8 = i & 7;
        *(short8*)(obuf + (size_t)b * 128 * 1024 + (size_t)h * 64
                   + (size_t)row * 1024 + c8 * 8) =
            *(const short8*)(os + row * 72 + c8 * 8);
    }
}

// ---------------------------------------------------------------------------
__global__ void pad_convert_inputs(const float* __restrict__ in, short* __restrict__ out)
{
    const int row = blockIdx.x;                 // [0, 16388)
    const int n = row / 8194, l = row % 8194;
    short* orow = out + (size_t)row * 4096;
    if (l == 0 || l == 8193) {
        for (int i = threadIdx.x; i < 512; i += 256) {
            uint4 z; z.x = z.y = z.z = z.w = 0u;
            *(uint4*)(orow + i * 8) = z;
        }
    } else {
        const float* irow = in + ((size_t)n * 8192 + (l - 1)) * 4096;
        for (int i = threadIdx.x; i < 512; i += 256) {
            float4 a = *(const float4*)(irow + i * 8);
            float4 b = *(const float4*)(irow + i * 8 + 4);
            short8 v;
            v[0] = f2bf(a.x); v[1] = f2bf(a.y); v[2] = f2bf(a.z); v[3] = f2bf(a.w);
            v[4] = f2bf(b.x); v[5] = f2bf(b.y); v[6] = f2bf(b.z); v[7] = f2bf(b.w);
            *(short8*)(orow + i * 8) = v;
        }
    }
}

__global__ void transpose_convert(const float* __restrict__ in, short* __restrict__ out,
                                  int R, int C)
{
    __shared__ float tile[32][33];
    const int tx = threadIdx.x & 31, ty = threadIdx.x >> 5;   // 32 x 8
    const int bx = blockIdx.x * 32, by = blockIdx.y * 32;
    #pragma unroll
    for (int i = 0; i < 32; i += 8)
        tile[ty + i][tx] = in[(size_t)(by + ty + i) * C + bx + tx];
    __syncthreads();
    #pragma unroll
    for (int i = 0; i < 32; i += 8)
        out[(size_t)(bx + ty + i) * R + by + tx] = f2bf(tile[tx][ty + i]);
}

__global__ void convert_bf16(const float* __restrict__ in, short* __restrict__ out, int n8)
{
    const int idx = blockIdx.x * 256 + threadIdx.x;
    if (idx < n8) {
        float4 a = *(const float4*)(in + (size_t)idx * 8);
        float4 b = *(const float4*)(in + (size_t)idx * 8 + 4);
        short8 v;
        v[0] = f2bf(a.x); v[1] = f2bf(a.y); v[2] = f2bf(a.z); v[3] = f2bf(a.w);
        v[4] = f2bf(b.x); v[5] = f2bf(b.y); v[6] = f2bf(b.z); v[7] = f2bf(b.w);
        *(short8*)(out + (size_t)idx * 8) = v;
    }
}

__global__ void fuse_bias(const float* __restrict__ bo, const float* __restrict__ projw,
                          const float* __restrict__ projb, float* __restrict__ outb)
{
    const int j = blockIdx.x * 256 + threadIdx.x;   // 4096
    float s = projb[j];
    for (int w = 0; w < 1024; ++w) s = fmaf(bo[w], projw[(size_t)w * 4096 + j], s);
    outb[j] = s;
}

// b2[o] = b_part[o&1023] + sum_d conv_b[(o>>10)*1024+d] * wpart[d][o&1023]
__global__ void fuse_bias_qkv(const float* __restrict__ conv_b,
                              const float* __restrict__ wq, const float* __restrict__ bq,
                              const float* __restrict__ wk, const float* __restrict__ bk,
                              const float* __restrict__ wv, const float* __restrict__ bv,
                              float* __restrict__ outb)
{
    const int o = blockIdx.x * 256 + threadIdx.x;   // 3072
    const int p = o >> 10, e = o & 1023;
    const float* w = (p == 0) ? wq : (p == 1) ? wk : wv;
    const float* bb = (p == 0) ? bq : (p == 1) ? bk : bv;
    const float* cb = conv_b + p * 1024;
    float s = bb[e];
    for (int d = 0; d < 1024; ++d) s = fmaf(cb[d], w[(size_t)d * 1024 + e], s);
    outb[o] = s;
}

// ---------------------------------------------------------------------------
extern "C" void kernel_launch(void* const* d_in, const int* in_sizes, int n_in,
                              void* d_out, int out_size, void* d_ws, size_t ws_size,
                              hipStream_t stream)
{
    const float* inputs = (const float*)d_in[0];
    const float* conv_w = (const float*)d_in[1];
    const float* conv_b = (const float*)d_in[2];
    const float* wq     = (const float*)d_in[3];
    const float* bq     = (const float*)d_in[4];
    const float* wk     = (const float*)d_in[5];
    const float* bk     = (const float*)d_in[6];
    const float* wv     = (const float*)d_in[7];
    const float* bv     = (const float*)d_in[8];
    const float* wo     = (const float*)d_in[9];
    const float* bo     = (const float*)d_in[10];
    const float* proj_w = (const float*)d_in[11];
    const float* proj_b = (const float*)d_in[12];

    char* ws = (char*)d_ws;
    short* in_pad = (short*)(ws + 0);             // [2][8194][4096]      134,283,264 B
    short* cw_bf  = (short*)(ws + 134283264);     // [3][4096][3072] bf16 (dead after prep)
    short* qkvh   = (short*)(ws + 134283264);     // [16384][3072] over cw_bf
    short* W2T    = (short*)(ws + 234946560);     // [3][3072][4096] bf16
    short* wq_t   = (short*)(ws + 310444032);     // [3][1024][1024] BT contiguous
    short* wo_bf  = (short*)(ws + 316735488);     // [1024][1024]
    short* proj_t = (short*)(ws + 318832640);     // [4096][1024]
    short* WfT    = (short*)(ws + 327221248);     // [4096][1024]
    float* bfused = (float*)(ws + 335609856);     // [4096]
    float* b2     = (float*)(ws + 335626240);     // [3072]
    short* o_buf  = (short*)(ws + 0);             // [16384][1024] over in_pad

    dim3 blk(256), blk5(512);

    pad_convert_inputs<<<16388, blk, 0, stream>>>(inputs, in_pad);
    convert_bf16<<<18432, blk, 0, stream>>>(conv_w, cw_bf, 4718592);   // straight convert
    transpose_convert<<<dim3(32, 32), blk, 0, stream>>>(wq, wq_t, 1024, 1024);
    transpose_convert<<<dim3(32, 32), blk, 0, stream>>>(wk, wq_t + 1048576, 1024, 1024);
    transpose_convert<<<dim3(32, 32), blk, 0, stream>>>(wv, wq_t + 2097152, 1024, 1024);
    transpose_convert<<<dim3(128, 32), blk, 0, stream>>>(proj_w, proj_t, 1024, 4096);
    convert_bf16<<<512, blk, 0, stream>>>(wo, wo_bf, 131072);
    fuse_bias<<<16, blk, 0, stream>>>(bo, proj_w, proj_b, bfused);
    fuse_bias_qkv<<<12, blk, 0, stream>>>(conv_b, wq, bq, wk, bk, wv, bv, b2);

    // WfT[dm][he] = sum_w proj_t[dm][w] * wo_flat[he][w]
    gemm256<1, 0, false><<<dim3(4, 16), blk5, 0, stream>>>(
        proj_t, 1024, wo_bf, 1024, 0, WfT, 1024, nullptr, 16);
    // weight prep: W2T[t][o][i] = sum_d wqkvT[o][d] * conv_w[t][i][(o>>10)*1024+d]
    for (int t = 0; t < 3; ++t)
        gemm256<1, 1, false><<<dim3(16, 12), blk5, 0, stream>>>(
            wq_t, 1024, cw_bf + (size_t)t * 4096 * 3072, 3072, 0,
            W2T + (size_t)t * 3072 * 4096, 4096, nullptr, 16);
    // fused conv+projection as 3-tap GEMM -> qkvh [16384][3072]
    gemm256<3, 0, false><<<dim3(12, 64), blk5, 0, stream>>>(
        in_pad, 4096, W2T, 4096, (long long)3072 * 4096, qkvh, 3072, b2, 192);

    attn_kernel<<<dim3(16, 128), blk, 0, stream>>>(qkvh, o_buf);

    // out = o @ Wf + bfused   (f32 out)
    gemm256<1, 0, true><<<dim3(16, 64), blk5, 0, stream>>>(
        o_buf, 1024, WfT, 1024, 0, d_out, 4096, bfused, 16);
}

// Round 14
// 1597.555 us; speedup vs baseline: 1.4075x; 1.1111x over previous
//
#include <hip/hip_runtime.h>
#include <hip/hip_bf16.h>
#include <stdint.h>

typedef __attribute__((ext_vector_type(8))) short short8;
typedef __attribute__((ext_vector_type(4))) float f32x4;

#define AS1 __attribute__((address_space(1)))
#define AS3 __attribute__((address_space(3)))

__device__ __forceinline__ short f2bf(float x) {
    __hip_bfloat16 h = __float2bfloat16(x);
    union { __hip_bfloat16 h; short s; } u; u.h = h; return u.s;
}

__device__ __forceinline__ void gload_lds16(const short* g, short* l) {
    __builtin_amdgcn_global_load_lds((const AS1 void*)g, (AS3 void*)l, 16, 0, 0);
}

#define SBAR()   __builtin_amdgcn_s_barrier()
#define WAITV(N) asm volatile("s_waitcnt vmcnt(" #N ")")
#define SCHED0() __builtin_amdgcn_sched_barrier(0)
#define VMCNT0_BAR() do { WAITV(0); SBAR(); SCHED0(); } while (0)

// ---------------------------------------------------------------------------
// conv3: fused 3-tap conv GEMM with TAP-SHARED A staging (r14).
// Diagnosis: rounds 1-13 plateaued at 45-47% MfmaUtil with VALUBusy only
// ~19% -- waves stall on operand fetch; staged traffic = 18.9 GB/dispatch
// (~26 B/cy/CU) served by L2/L3 near its BW ceiling. Taps overlap 99% in A,
// yet were staged 3x. Here: BK=32 steps; per step stage A ONCE ([272][32]
// window; rows 256-271 by one extra wave-7 gload; tail-tile OOB reads stay
// inside d_ws and land in unused LDS rows) + B for 3 taps ([3][256][32]).
// Per-step staged bytes 96 KB -> 65 KB (-33%); syncs per K-work / 3.
// Tap t's A-fragment reads at row+t (ds_read any base); chunk-XOR swizzle
// slot = g ^ ((row>>1)&3) with per-tap constant ((c15+t)>>1)&3 -- same
// staging/read involution as r5 (measured 0 conflicts).
// One sync per step: vmcnt(0)+s_barrier (stage issued a full step earlier).
// Hazard: stage(s+1 -> buf^1) follows barrier(s); all reads(s-1) of buf^1
// retired before their MFMAs, which precede barrier(s). Safe.
// ---------------------------------------------------------------------------
__global__ __launch_bounds__(512, 2) void conv3_gemm(
    const short* __restrict__ A,        // in_pad [2*8194][4096]
    const short* __restrict__ BT,       // W2T [3][3072][4096]
    short* __restrict__ Cout,           // qkvh [16384][3072]
    const float* __restrict__ bias)     // b2 [3072]
{
    __shared__ __align__(16) short As[2 * 272 * 32];      //  34,816 B
    __shared__ __align__(16) short Bs[2 * 3 * 256 * 32];  //  98,304 B
    const int tid = threadIdx.x, lane = tid & 63, wid = tid >> 6;
    const int wm = wid >> 2, wn = wid & 3;
    const int m0 = blockIdx.y * 256, n0 = blockIdx.x * 256;
    const size_t arow0 = (size_t)(m0 >> 13) * 8194 + (size_t)(m0 & 8191);
    const short* Abase = A + arow0 * 4096;
    const short* Bbase = BT + (size_t)n0 * 4096;
    const int c15 = lane & 15, g = lane >> 4, g4 = g * 4;
    const int xr0 = (c15 >> 1) & 3;            // tap-0 row-XOR
    const int xr1 = ((c15 + 1) >> 1) & 3;      // tap-1
    const int xr2 = ((c15 + 2) >> 1) & 3;      // tap-2
    const int srow = tid >> 2;
    const int schunk = (((tid & 3) ^ ((tid >> 3) & 3)) * 8);
    const int srowX = lane >> 2;               // wave-7 extra rows 256-271
    const int schunkX = (((lane & 3) ^ ((lane >> 3) & 3)) * 8);

#define STAGE(s, buf) do { \
    const int kc_ = (s) * 32; \
    const short* ga_ = Abase + (size_t)srow * 4096 + kc_ + schunk; \
    short* la_ = As + (buf) * 8704 + wid * 512; \
    gload_lds16(ga_, la_); \
    gload_lds16(ga_ + 128 * 4096, la_ + 4096); \
    if (wid == 7) \
        gload_lds16(Abase + (size_t)(256 + srowX) * 4096 + kc_ + schunkX, \
                    As + (buf) * 8704 + 256 * 32); \
    _Pragma("unroll") \
    for (int tp_ = 0; tp_ < 3; ++tp_) { \
        const short* gb_ = Bbase + (size_t)tp_ * 3072 * 4096 \
                           + (size_t)srow * 4096 + kc_ + schunk; \
        short* lb_ = Bs + (buf) * 24576 + tp_ * 8192 + wid * 512; \
        gload_lds16(gb_, lb_); \
        gload_lds16(gb_ + 128 * 4096, lb_ + 4096); \
    } \
} while (0)

// A frag: tap t, row-block mi -> physical row wm*128+mi*16+c15+t
#define LDA_T(buf, mi, T, XR) (*(const short8*)(As + (buf) * 8704 \
    + (wm * 128 + (mi) * 16 + c15 + (T)) * 32 + ((g ^ (XR)) * 8)))
// B frag: tap t, col-block nj
#define LDB_T(buf, tp, nj) (*(const short8*)(Bs + (buf) * 24576 + (tp) * 8192 \
    + (wn * 64 + (nj) * 16 + c15) * 32 + ((g ^ xr0) * 8)))

    f32x4 acc[8][4];
    #pragma unroll
    for (int i = 0; i < 8; ++i)
        #pragma unroll
        for (int j = 0; j < 4; ++j)
            acc[i][j] = (f32x4){0.f, 0.f, 0.f, 0.f};

    STAGE(0, 0);

    for (int s = 0; s < 128; ++s) {
        const int c = s & 1;
        VMCNT0_BAR();                       // buf c resident
        if (s + 1 < 128) STAGE(s + 1, c ^ 1);
        #pragma unroll
        for (int tp = 0; tp < 3; ++tp) {
            const int xr = (tp == 0) ? xr0 : (tp == 1) ? xr1 : xr2;
            short8 b0 = LDB_T(c, tp, 0), b1 = LDB_T(c, tp, 1);
            short8 b2f = LDB_T(c, tp, 2), b3 = LDB_T(c, tp, 3);
            __builtin_amdgcn_s_setprio(1);
            #pragma unroll
            for (int mi = 0; mi < 8; ++mi) {
                short8 a = LDA_T(c, mi, tp, xr);
                acc[mi][0] = __builtin_amdgcn_mfma_f32_16x16x32_bf16(a, b0, acc[mi][0], 0, 0, 0);
                acc[mi][1] = __builtin_amdgcn_mfma_f32_16x16x32_bf16(a, b1, acc[mi][1], 0, 0, 0);
                acc[mi][2] = __builtin_amdgcn_mfma_f32_16x16x32_bf16(a, b2f, acc[mi][2], 0, 0, 0);
                acc[mi][3] = __builtin_amdgcn_mfma_f32_16x16x32_bf16(a, b3, acc[mi][3], 0, 0, 0);
            }
            __builtin_amdgcn_s_setprio(0);
        }
    }

    float bv[4];
    #pragma unroll
    for (int nj = 0; nj < 4; ++nj)
        bv[nj] = bias[n0 + wn * 64 + nj * 16 + c15];
    #pragma unroll
    for (int mi = 0; mi < 8; ++mi) {
        #pragma unroll
        for (int r = 0; r < 4; ++r) {
            const size_t row = (size_t)m0 + wm * 128 + mi * 16 + g4 + r;
            #pragma unroll
            for (int nj = 0; nj < 4; ++nj) {
                const int col = n0 + wn * 64 + nj * 16 + c15;
                Cout[row * 3072 + col] = f2bf(acc[mi][nj][r] + bv[nj]);
            }
        }
    }
#undef STAGE
#undef LDA_T
#undef LDB_T
}

// ---------------------------------------------------------------------------
// r11 gemm256 (best measured general GEMM): 256x256, BK=64, 8 waves, 4 phases
// split on mi, counted vmcnt(4), chunk-XOR swizzle (0 conflicts), setprio.
// MODE: 0 = plain; 1 = QKVB (weight-prep: B col base += m0 & ~1023).
// ---------------------------------------------------------------------------
template<int MODE, bool F32OUT>
__global__ __launch_bounds__(512, 2) void gemm256(
    const short* __restrict__ A, int lda,
    const short* __restrict__ BT, int ldb,
    void* __restrict__ Cout, int ldc,
    const float* __restrict__ bias, int Ktiles)
{
    __shared__ __align__(16) short As[2 * 2 * 256 * 32];
    __shared__ __align__(16) short Bs[2 * 2 * 256 * 32];
    const int tid = threadIdx.x, lane = tid & 63, wid = tid >> 6;
    const int wm = wid >> 2, wn = wid & 3;
    const int m0 = blockIdx.y * 256, n0 = blockIdx.x * 256;
    const size_t ldaS = (size_t)lda, ldbS = (size_t)ldb;
    const short* Abase0 = A + (size_t)m0 * ldaS;
    const short* Bbase0 = BT + (size_t)n0 * ldbS + ((MODE == 1) ? (m0 & ~1023) : 0);
    const int c15 = lane & 15, g4 = (lane >> 4) * 4;
    const int swz = ((lane >> 4) ^ ((c15 >> 1) & 3)) * 8;
    const int srow = tid >> 2;
    const int schunk = (((tid & 3) ^ ((tid >> 3) & 3)) * 8);

#define STG_A(u, kh, buf) do { \
    const short* g_ = Abase0 + ((u) << 6) + (kh) * 32 + (size_t)srow * ldaS + schunk; \
    short* l_ = As + (buf) * 16384 + (kh) * 8192 + wid * 512; \
    gload_lds16(g_, l_); \
    gload_lds16(g_ + 128 * ldaS, l_ + 4096); \
} while (0)

#define STG_B(u, kh, buf) do { \
    const short* g_ = Bbase0 + ((u) << 6) + (kh) * 32 + (size_t)srow * ldbS + schunk; \
    short* l_ = Bs + (buf) * 16384 + (kh) * 8192 + wid * 512; \
    gload_lds16(g_, l_); \
    gload_lds16(g_ + 128 * ldbS, l_ + 4096); \
} while (0)

#define LDA_(buf, kk, mi) (*(const short8*)(As + (buf) * 16384 + (kk) * 8192 \
                           + (wm * 128 + (mi) * 16 + c15) * 32 + swz))
#define LDB_(buf, kk, nj) (*(const short8*)(Bs + (buf) * 16384 + (kk) * 8192 \
                           + (wn * 64 + (nj) * 16 + c15) * 32 + swz))

#define MFMA4x4(MB) do { \
    __builtin_amdgcn_s_setprio(1); \
    _Pragma("unroll") \
    for (int mi_ = 0; mi_ < 4; ++mi_) \
        _Pragma("unroll") \
        for (int nj_ = 0; nj_ < 4; ++nj_) \
            acc[(MB) + mi_][nj_] = __builtin_amdgcn_mfma_f32_16x16x32_bf16( \
                af[mi_], bf4[nj_], acc[(MB) + mi_][nj_], 0, 0, 0); \
    __builtin_amdgcn_s_setprio(0); \
} while (0)

    f32x4 acc[8][4];
    #pragma unroll
    for (int i = 0; i < 8; ++i)
        #pragma unroll
        for (int j = 0; j < 4; ++j)
            acc[i][j] = (f32x4){0.f, 0.f, 0.f, 0.f};

    STG_A(0, 0, 0); STG_B(0, 0, 0); STG_A(0, 1, 0); STG_B(0, 1, 0);
    WAITV(4); SBAR(); SCHED0();

    for (int t = 0; t < Ktiles; ++t) {
        const int c = t & 1, nb = c ^ 1;
        const bool st = (t + 1 < Ktiles);
        const int u = t + 1;
        short8 af[4], bf4[4];

        #pragma unroll
        for (int mi = 0; mi < 4; ++mi) af[mi] = LDA_(c, 0, mi);
        #pragma unroll
        for (int nj = 0; nj < 4; ++nj) bf4[nj] = LDB_(c, 0, nj);
        if (st) STG_A(u, 0, nb);
        SBAR();
        MFMA4x4(0);
        SBAR();

        #pragma unroll
        for (int mi = 0; mi < 4; ++mi) af[mi] = LDA_(c, 0, 4 + mi);
        if (st) STG_B(u, 0, nb);
        if (st) { WAITV(4); } else { WAITV(0); }
        SBAR(); SCHED0();
        MFMA4x4(4);
        SBAR();

        #pragma unroll
        for (int mi = 0; mi < 4; ++mi) af[mi] = LDA_(c, 1, mi);
        #pragma unroll
        for (int nj = 0; nj < 4; ++nj) bf4[nj] = LDB_(c, 1, nj);
        if (st) STG_A(u, 1, nb);
        SBAR();
        MFMA4x4(0);
        SBAR();

        #pragma unroll
        for (int mi = 0; mi < 4; ++mi) af[mi] = LDA_(c, 1, 4 + mi);
        if (st) STG_B(u, 1, nb);
        if (st) { WAITV(4); } else { WAITV(0); }
        SBAR(); SCHED0();
        MFMA4x4(4);
        SBAR();
    }

    float bv[4];
    #pragma unroll
    for (int nj = 0; nj < 4; ++nj)
        bv[nj] = bias ? bias[n0 + wn * 64 + nj * 16 + c15] : 0.f;
    #pragma unroll
    for (int mi = 0; mi < 8; ++mi) {
        #pragma unroll
        for (int r = 0; r < 4; ++r) {
            const size_t row = (size_t)m0 + wm * 128 + mi * 16 + g4 + r;
            #pragma unroll
            for (int nj = 0; nj < 4; ++nj) {
                const int col = n0 + wn * 64 + nj * 16 + c15;
                const float v = acc[mi][nj][r] + bv[nj];
                if (F32OUT) ((float*)Cout)[row * (size_t)ldc + col] = v;
                else        ((short*)Cout)[row * (size_t)ldc + col] = f2bf(v);
            }
        }
    }
#undef STG_A
#undef STG_B
#undef LDA_
#undef LDB_
#undef MFMA4x4
}

// ---------------------------------------------------------------------------
// Per (head, block) causal attention. qkvh: [16384][3072] bf16, q at cols
// 0-1023, k at +1024, v at +2048 (col within each = h*64+e). obuf [16384][1024].
// ---------------------------------------------------------------------------
__global__ __launch_bounds__(256) void attn_kernel(
    const short* __restrict__ qkvh, short* __restrict__ obuf)
{
    __shared__ __align__(16) char smem[54272];
    short* qs = (short*)smem;                 // [128][72]
    short* ks = (short*)smem + 9216;          // [128][72]
    short* vt = (short*)(smem + 36864);       // [64][136]  (v transposed)
    short* ps = (short*)smem;                 // [128][136] (reuses qs+ks region)
    short* os = (short*)smem;                 // [128][72]  (reused post-PV)

    const int tid = threadIdx.x, lane = tid & 63, wid = tid >> 6;
    const int h = blockIdx.x, b = blockIdx.y;
    const size_t base = (size_t)b * 128 * 3072 + (size_t)h * 64;

    for (int i = tid; i < 1024; i += 256) {
        const int row = i >> 3, c8 = i & 7;
        const size_t g = base + (size_t)row * 3072 + c8 * 8;
        *(short8*)(qs + row * 72 + c8 * 8) = *(const short8*)(qkvh + g);
        *(short8*)(ks + row * 72 + c8 * 8) = *(const short8*)(qkvh + g + 1024);
        short8 vv = *(const short8*)(qkvh + g + 2048);
        #pragma unroll
        for (int j = 0; j < 8; ++j) vt[(c8 * 8 + j) * 136 + row] = vv[j];
    }
    __syncthreads();

    const int c15 = lane & 15, g8 = (lane >> 4) * 8, g4 = (lane >> 4) * 4;
    const int r0 = wid * 32;

    f32x4 sacc[2][8];
    #pragma unroll
    for (int mi = 0; mi < 2; ++mi)
        #pragma unroll
        for (int nj = 0; nj < 8; ++nj)
            sacc[mi][nj] = (f32x4){0.f, 0.f, 0.f, 0.f};
    #pragma unroll
    for (int kk = 0; kk < 2; ++kk) {
        short8 aq[2];
        #pragma unroll
        for (int mi = 0; mi < 2; ++mi)
            aq[mi] = *(const short8*)(qs + (r0 + mi * 16 + c15) * 72 + kk * 32 + g8);
        #pragma unroll
        for (int nj = 0; nj < 8; ++nj) {
            short8 bk8 = *(const short8*)(ks + (nj * 16 + c15) * 72 + kk * 32 + g8);
            #pragma unroll
            for (int mi = 0; mi < 2; ++mi)
                sacc[mi][nj] = __builtin_amdgcn_mfma_f32_16x16x32_bf16(
                    aq[mi], bk8, sacc[mi][nj], 0, 0, 0);
        }
    }
    __syncthreads();

    #pragma unroll
    for (int mi = 0; mi < 2; ++mi) {
        #pragma unroll
        for (int r = 0; r < 4; ++r) {
            const int qrow = r0 + mi * 16 + g4 + r;
            float m = -3.0e38f, pv[8];
            #pragma unroll
            for (int nj = 0; nj < 8; ++nj) {
                float s = sacc[mi][nj][r] * 0.125f;
                if (nj * 16 + c15 > qrow) s = -1.0e9f;
                pv[nj] = s; m = fmaxf(m, s);
            }
            #pragma unroll
            for (int off = 8; off >= 1; off >>= 1) m = fmaxf(m, __shfl_xor(m, off));
            float sum = 0.f;
            #pragma unroll
            for (int nj = 0; nj < 8; ++nj) { float p = __expf(pv[nj] - m); pv[nj] = p; sum += p; }
            #pragma unroll
            for (int off = 8; off >= 1; off >>= 1) sum += __shfl_xor(sum, off);
            const float inv = 1.0f / sum;
            #pragma unroll
            for (int nj = 0; nj < 8; ++nj)
                ps[qrow * 136 + nj * 16 + c15] = f2bf(pv[nj] * inv);
        }
    }
    __syncthreads();

    f32x4 oacc[2][4];
    #pragma unroll
    for (int mi = 0; mi < 2; ++mi)
        #pragma unroll
        for (int nj = 0; nj < 4; ++nj)
            oacc[mi][nj] = (f32x4){0.f, 0.f, 0.f, 0.f};
    #pragma unroll
    for (int kt = 0; kt < 4; ++kt) {
        short8 ap[2];
        #pragma unroll
        for (int mi = 0; mi < 2; ++mi)
            ap[mi] = *(const short8*)(ps + (r0 + mi * 16 + c15) * 136 + kt * 32 + g8);
        #pragma unroll
        for (int nj = 0; nj < 4; ++nj) {
            short8 bv8 = *(const short8*)(vt + (nj * 16 + c15) * 136 + kt * 32 + g8);
            #pragma unroll
            for (int mi = 0; mi < 2; ++mi)
                oacc[mi][nj] = __builtin_amdgcn_mfma_f32_16x16x32_bf16(
                    ap[mi], bv8, oacc[mi][nj], 0, 0, 0);
        }
    }
    __syncthreads();

    #pragma unroll
    for (int mi = 0; mi < 2; ++mi)
        #pragma unroll
        for (int r = 0; r < 4; ++r)
            #pragma unroll
            for (int nj = 0; nj < 4; ++nj)
                os[(r0 + mi * 16 + g4 + r) * 72 + nj * 16 + c15] = f2bf(oacc[mi][nj][r]);
    __syncthreads();

    for (int i = tid; i < 1024; i += 256) {
        const int row = i >> 3, c8 = i & 7;
        *(short8*)(obuf + (size_t)b * 128 * 1024 + (size_t)h * 64
                   + (size_t)row * 1024 + c8 * 8) =
            *(const short8*)(os + row * 72 + c8 * 8);
    }
}

// ---------------------------------------------------------------------------
__global__ void pad_convert_inputs(const float* __restrict__ in, short* __restrict__ out)
{
    const int row = blockIdx.x;                 // [0, 16388)
    const int n = row / 8194, l = row % 8194;
    short* orow = out + (size_t)row * 4096;
    if (l == 0 || l == 8193) {
        for (int i = threadIdx.x; i < 512; i += 256) {
            uint4 z; z.x = z.y = z.z = z.w = 0u;
            *(uint4*)(orow + i * 8) = z;
        }
    } else {
        const float* irow = in + ((size_t)n * 8192 + (l - 1)) * 4096;
        for (int i = threadIdx.x; i < 512; i += 256) {
            float4 a = *(const float4*)(irow + i * 8);
            float4 b = *(const float4*)(irow + i * 8 + 4);
            short8 v;
            v[0] = f2bf(a.x); v[1] = f2bf(a.y); v[2] = f2bf(a.z); v[3] = f2bf(a.w);
            v[4] = f2bf(b.x); v[5] = f2bf(b.y); v[6] = f2bf(b.z); v[7] = f2bf(b.w);
            *(short8*)(orow + i * 8) = v;
        }
    }
}

__global__ void transpose_convert(const float* __restrict__ in, short* __restrict__ out,
                                  int R, int C)
{
    __shared__ float tile[32][33];
    const int tx = threadIdx.x & 31, ty = threadIdx.x >> 5;   // 32 x 8
    const int bx = blockIdx.x * 32, by = blockIdx.y * 32;
    #pragma unroll
    for (int i = 0; i < 32; i += 8)
        tile[ty + i][tx] = in[(size_t)(by + ty + i) * C + bx + tx];
    __syncthreads();
    #pragma unroll
    for (int i = 0; i < 32; i += 8)
        out[(size_t)(bx + ty + i) * R + by + tx] = f2bf(tile[tx][ty + i]);
}

__global__ void convert_bf16(const float* __restrict__ in, short* __restrict__ out, int n8)
{
    const int idx = blockIdx.x * 256 + threadIdx.x;
    if (idx < n8) {
        float4 a = *(const float4*)(in + (size_t)idx * 8);
        float4 b = *(const float4*)(in + (size_t)idx * 8 + 4);
        short8 v;
        v[0] = f2bf(a.x); v[1] = f2bf(a.y); v[2] = f2bf(a.z); v[3] = f2bf(a.w);
        v[4] = f2bf(b.x); v[5] = f2bf(b.y); v[6] = f2bf(b.z); v[7] = f2bf(b.w);
        *(short8*)(out + (size_t)idx * 8) = v;
    }
}

__global__ void fuse_bias(const float* __restrict__ bo, const float* __restrict__ projw,
                          const float* __restrict__ projb, float* __restrict__ outb)
{
    const int j = blockIdx.x * 256 + threadIdx.x;   // 4096
    float s = projb[j];
    for (int w = 0; w < 1024; ++w) s = fmaf(bo[w], projw[(size_t)w * 4096 + j], s);
    outb[j] = s;
}

// b2[o] = b_part[o&1023] + sum_d conv_b[(o>>10)*1024+d] * wpart[d][o&1023]
__global__ void fuse_bias_qkv(const float* __restrict__ conv_b,
                              const float* __restrict__ wq, const float* __restrict__ bq,
                              const float* __restrict__ wk, const float* __restrict__ bk,
                              const float* __restrict__ wv, const float* __restrict__ bv,
                              float* __restrict__ outb)
{
    const int o = blockIdx.x * 256 + threadIdx.x;   // 3072
    const int p = o >> 10, e = o & 1023;
    const float* w = (p == 0) ? wq : (p == 1) ? wk : wv;
    const float* bb = (p == 0) ? bq : (p == 1) ? bk : bv;
    const float* cb = conv_b + p * 1024;
    float s = bb[e];
    for (int d = 0; d < 1024; ++d) s = fmaf(cb[d], w[(size_t)d * 1024 + e], s);
    outb[o] = s;
}

// ---------------------------------------------------------------------------
extern "C" void kernel_launch(void* const* d_in, const int* in_sizes, int n_in,
                              void* d_out, int out_size, void* d_ws, size_t ws_size,
                              hipStream_t stream)
{
    const float* inputs = (const float*)d_in[0];
    const float* conv_w = (const float*)d_in[1];
    const float* conv_b = (const float*)d_in[2];
    const float* wq     = (const float*)d_in[3];
    const float* bq     = (const float*)d_in[4];
    const float* wk     = (const float*)d_in[5];
    const float* bk     = (const float*)d_in[6];
    const float* wv     = (const float*)d_in[7];
    const float* bv     = (const float*)d_in[8];
    const float* wo     = (const float*)d_in[9];
    const float* bo     = (const float*)d_in[10];
    const float* proj_w = (const float*)d_in[11];
    const float* proj_b = (const float*)d_in[12];

    char* ws = (char*)d_ws;
    short* in_pad = (short*)(ws + 0);             // [2][8194][4096]      134,283,264 B
    short* cw_bf  = (short*)(ws + 134283264);     // [3][4096][3072] bf16 (dead after prep)
    short* qkvh   = (short*)(ws + 134283264);     // [16384][3072] over cw_bf
    short* W2T    = (short*)(ws + 234946560);     // [3][3072][4096] bf16
    short* wq_t   = (short*)(ws + 310444032);     // [3][1024][1024] BT contiguous
    short* wo_bf  = (short*)(ws + 316735488);     // [1024][1024]
    short* proj_t = (short*)(ws + 318832640);     // [4096][1024]
    short* WfT    = (short*)(ws + 327221248);     // [4096][1024]
    float* bfused = (float*)(ws + 335609856);     // [4096]
    float* b2     = (float*)(ws + 335626240);     // [3072]
    short* o_buf  = (short*)(ws + 0);             // [16384][1024] over in_pad

    dim3 blk(256), blk5(512);

    pad_convert_inputs<<<16388, blk, 0, stream>>>(inputs, in_pad);
    convert_bf16<<<18432, blk, 0, stream>>>(conv_w, cw_bf, 4718592);   // straight convert
    transpose_convert<<<dim3(32, 32), blk, 0, stream>>>(wq, wq_t, 1024, 1024);
    transpose_convert<<<dim3(32, 32), blk, 0, stream>>>(wk, wq_t + 1048576, 1024, 1024);
    transpose_convert<<<dim3(32, 32), blk, 0, stream>>>(wv, wq_t + 2097152, 1024, 1024);
    transpose_convert<<<dim3(128, 32), blk, 0, stream>>>(proj_w, proj_t, 1024, 4096);
    convert_bf16<<<512, blk, 0, stream>>>(wo, wo_bf, 131072);
    fuse_bias<<<16, blk, 0, stream>>>(bo, proj_w, proj_b, bfused);
    fuse_bias_qkv<<<12, blk, 0, stream>>>(conv_b, wq, bq, wk, bk, wv, bv, b2);

    // WfT[dm][he] = sum_w proj_t[dm][w] * wo_flat[he][w]
    gemm256<0, false><<<dim3(4, 16), blk5, 0, stream>>>(
        proj_t, 1024, wo_bf, 1024, WfT, 1024, nullptr, 16);
    // weight prep: W2T[t][o][i] = sum_d wqkvT[o][d] * conv_w[t][i][(o>>10)*1024+d]
    for (int t = 0; t < 3; ++t)
        gemm256<1, false><<<dim3(16, 12), blk5, 0, stream>>>(
            wq_t, 1024, cw_bf + (size_t)t * 4096 * 3072, 3072,
            W2T + (size_t)t * 3072 * 4096, 4096, nullptr, 16);
    // fused conv+projection, tap-shared A staging -> qkvh [16384][3072]
    conv3_gemm<<<dim3(12, 64), blk5, 0, stream>>>(in_pad, W2T, qkvh, b2);

    attn_kernel<<<dim3(16, 128), blk, 0, stream>>>(qkvh, o_buf);

    // out = o @ Wf + bfused   (f32 out)
    gemm256<0, true><<<dim3(16, 64), blk5, 0, stream>>>(
        o_buf, 1024, WfT, 1024, d_out, 4096, bfused, 16);
}

// Round 15
// 1494.486 us; speedup vs baseline: 1.5045x; 1.0690x over previous
//
#include <hip/hip_runtime.h>
#include <hip/hip_bf16.h>
#include <stdint.h>

typedef __attribute__((ext_vector_type(8))) short short8;
typedef __attribute__((ext_vector_type(4))) float f32x4;

#define AS1 __attribute__((address_space(1)))
#define AS3 __attribute__((address_space(3)))

__device__ __forceinline__ short f2bf(float x) {
    __hip_bfloat16 h = __float2bfloat16(x);
    union { __hip_bfloat16 h; short s; } u; u.h = h; return u.s;
}

__device__ __forceinline__ void gload_lds16(const short* g, short* l) {
    __builtin_amdgcn_global_load_lds((const AS1 void*)g, (AS3 void*)l, 16, 0, 0);
}

#define SBAR()   __builtin_amdgcn_s_barrier()
#define WAITV(N) asm volatile("s_waitcnt vmcnt(" #N ")")
#define SCHED0() __builtin_amdgcn_sched_barrier(0)

// ---------------------------------------------------------------------------
// conv3 (r15): 3 blocks/CU. r14's model fit exactly (step = MFMA 3725 +
// LDS 3776 + sync, fully serialized at 1 block/CU -- barrier lockstep gives
// the LDS port nothing to overlap with). Fix occupancy, not schedule:
// 256-thread blocks (4 waves, 2wm x 2wn, per-wave 128x64), tile 256x128,
// BK=32, SINGLE-buffered A[258][32] + B[3][128][32] = 41 KB LDS -> 3
// blocks/CU; co-resident blocks overlap MFMA vs LDS phases (m114).
// Step: {vmcnt(0); s_barrier; reads+MFMA(3 taps); s_barrier; STAGE(s+1)}.
// Hazards: (1) per-wave vmcnt BEFORE barrier -> after barrier ALL waves'
// stage loads are retired (each wave drained its own, barrier publishes).
// (2) single-buffer overwrite: reads(s) complete (data in regs; lgkm waits
// precede the consuming MFMAs) before the end barrier; STAGE(s+1) issues
// after it. Staging involutions: XOR term ((row>>1)&3) is invariant under
// +16/+64-row shifts (multiples of 8 after >>1); rows 256/257 have XOR=0.
// Read-side XOR per tap: ((c15+T)>>1)&3 (handles c15+T >= 16 since row base
// is a multiple of 16). Conflict-free (measured 0 in r14, same involution).
// ---------------------------------------------------------------------------
__global__ __launch_bounds__(256, 3) void conv3_gemm(
    const short* __restrict__ A,        // in_pad [2*8194][4096]
    const short* __restrict__ BT,       // W2T [3][3072][4096]
    short* __restrict__ Cout,           // qkvh [16384][3072]
    const float* __restrict__ bias)     // b2 [3072]
{
    __shared__ __align__(16) short As[258 * 32];      // 16,512 B
    __shared__ __align__(16) short Bs[3 * 128 * 32];  // 24,576 B
    const int tid = threadIdx.x, lane = tid & 63, wid = tid >> 6;
    const int wm = wid >> 1, wn = wid & 1;
    const int m0 = blockIdx.y * 256, n0 = blockIdx.x * 128;
    const size_t arow0 = (size_t)(m0 >> 13) * 8194 + (size_t)(m0 & 8191);
    const short* Abase = A + arow0 * 4096;
    const short* Bbase = BT + (size_t)n0 * 4096;
    const int c15 = lane & 15, g = lane >> 4, g4 = g * 4;
    const int xr0 = (c15 >> 1) & 3;            // tap-0 row-XOR
    const int xr1 = ((c15 + 1) >> 1) & 3;      // tap-1
    const int xr2 = ((c15 + 2) >> 1) & 3;      // tap-2
    const int srow = tid >> 2;                           // 0..63
    const int schunk = (((tid & 3) ^ ((tid >> 3) & 3)) * 8);
    const int srowB = wid * 32 + (lane >> 2);            // B row in tile
    const int schunkB = (((lane & 3) ^ ((lane >> 3) & 3)) * 8);

#define STAGE(s) do { \
    const int kc_ = (s) * 32; \
    const short* ga_ = Abase + (size_t)srow * 4096 + kc_ + schunk; \
    short* la_ = As + wid * 512; \
    gload_lds16(ga_, la_); \
    gload_lds16(ga_ + (size_t)64 * 4096, la_ + 2048); \
    gload_lds16(ga_ + (size_t)128 * 4096, la_ + 4096); \
    gload_lds16(ga_ + (size_t)192 * 4096, la_ + 6144); \
    if (wid == 3 && lane < 8) \
        gload_lds16(Abase + (size_t)(256 + (lane >> 2)) * 4096 + kc_ + (lane & 3) * 8, \
                    As + 8192); \
    _Pragma("unroll") \
    for (int tp_ = 0; tp_ < 3; ++tp_) { \
        const short* gb_ = Bbase + (size_t)tp_ * 3072 * 4096 \
                           + (size_t)srowB * 4096 + kc_ + schunkB; \
        short* lb_ = Bs + tp_ * 4096 + wid * 1024; \
        gload_lds16(gb_, lb_); \
        gload_lds16(gb_ + (size_t)16 * 4096, lb_ + 512); \
    } \
} while (0)

// A frag: tap T, row-block mi -> row wm*128 + mi*16 + c15 + T
#define LDA_T(mi, T, XR) (*(const short8*)(As \
    + (wm * 128 + (mi) * 16 + c15 + (T)) * 32 + ((g ^ (XR)) * 8)))
// B frag: tap tp, col-block nj -> row wn*64 + nj*16 + c15
#define LDB_T(tp, nj) (*(const short8*)(Bs + (tp) * 4096 \
    + (wn * 64 + (nj) * 16 + c15) * 32 + ((g ^ xr0) * 8)))

    f32x4 acc[8][4];
    #pragma unroll
    for (int i = 0; i < 8; ++i)
        #pragma unroll
        for (int j = 0; j < 4; ++j)
            acc[i][j] = (f32x4){0.f, 0.f, 0.f, 0.f};

    STAGE(0);

    for (int s = 0; s < 128; ++s) {
        WAITV(0); SBAR(); SCHED0();          // all waves' stage loads retired
        #pragma unroll
        for (int tp = 0; tp < 3; ++tp) {
            const int xr = (tp == 0) ? xr0 : (tp == 1) ? xr1 : xr2;
            short8 b0 = LDB_T(tp, 0), b1 = LDB_T(tp, 1);
            short8 b2f = LDB_T(tp, 2), b3 = LDB_T(tp, 3);
            __builtin_amdgcn_s_setprio(1);
            #pragma unroll
            for (int mi = 0; mi < 8; ++mi) {
                short8 a = LDA_T(mi, tp, xr);
                acc[mi][0] = __builtin_amdgcn_mfma_f32_16x16x32_bf16(a, b0, acc[mi][0], 0, 0, 0);
                acc[mi][1] = __builtin_amdgcn_mfma_f32_16x16x32_bf16(a, b1, acc[mi][1], 0, 0, 0);
                acc[mi][2] = __builtin_amdgcn_mfma_f32_16x16x32_bf16(a, b2f, acc[mi][2], 0, 0, 0);
                acc[mi][3] = __builtin_amdgcn_mfma_f32_16x16x32_bf16(a, b3, acc[mi][3], 0, 0, 0);
            }
            __builtin_amdgcn_s_setprio(0);
        }
        SBAR();                               // all reads(s) done (in regs)
        if (s + 1 < 128) STAGE(s + 1);        // safe to overwrite
    }

    float bv[4];
    #pragma unroll
    for (int nj = 0; nj < 4; ++nj)
        bv[nj] = bias[n0 + wn * 64 + nj * 16 + c15];
    #pragma unroll
    for (int mi = 0; mi < 8; ++mi) {
        #pragma unroll
        for (int r = 0; r < 4; ++r) {
            const size_t row = (size_t)m0 + wm * 128 + mi * 16 + g4 + r;
            #pragma unroll
            for (int nj = 0; nj < 4; ++nj) {
                const int col = n0 + wn * 64 + nj * 16 + c15;
                Cout[row * 3072 + col] = f2bf(acc[mi][nj][r] + bv[nj]);
            }
        }
    }
#undef STAGE
#undef LDA_T
#undef LDB_T
}

// ---------------------------------------------------------------------------
// r11 gemm256 (best measured general GEMM): 256x256, BK=64, 8 waves, 4 phases
// split on mi, counted vmcnt(4), chunk-XOR swizzle (0 conflicts), setprio.
// MODE: 0 = plain; 1 = QKVB (weight-prep: B col base += m0 & ~1023).
// ---------------------------------------------------------------------------
template<int MODE, bool F32OUT>
__global__ __launch_bounds__(512, 2) void gemm256(
    const short* __restrict__ A, int lda,
    const short* __restrict__ BT, int ldb,
    void* __restrict__ Cout, int ldc,
    const float* __restrict__ bias, int Ktiles)
{
    __shared__ __align__(16) short As[2 * 2 * 256 * 32];
    __shared__ __align__(16) short Bs[2 * 2 * 256 * 32];
    const int tid = threadIdx.x, lane = tid & 63, wid = tid >> 6;
    const int wm = wid >> 2, wn = wid & 3;
    const int m0 = blockIdx.y * 256, n0 = blockIdx.x * 256;
    const size_t ldaS = (size_t)lda, ldbS = (size_t)ldb;
    const short* Abase0 = A + (size_t)m0 * ldaS;
    const short* Bbase0 = BT + (size_t)n0 * ldbS + ((MODE == 1) ? (m0 & ~1023) : 0);
    const int c15 = lane & 15, g4 = (lane >> 4) * 4;
    const int swz = ((lane >> 4) ^ ((c15 >> 1) & 3)) * 8;
    const int srow = tid >> 2;
    const int schunk = (((tid & 3) ^ ((tid >> 3) & 3)) * 8);

#define STG_A(u, kh, buf) do { \
    const short* g_ = Abase0 + ((u) << 6) + (kh) * 32 + (size_t)srow * ldaS + schunk; \
    short* l_ = As + (buf) * 16384 + (kh) * 8192 + wid * 512; \
    gload_lds16(g_, l_); \
    gload_lds16(g_ + 128 * ldaS, l_ + 4096); \
} while (0)

#define STG_B(u, kh, buf) do { \
    const short* g_ = Bbase0 + ((u) << 6) + (kh) * 32 + (size_t)srow * ldbS + schunk; \
    short* l_ = Bs + (buf) * 16384 + (kh) * 8192 + wid * 512; \
    gload_lds16(g_, l_); \
    gload_lds16(g_ + 128 * ldbS, l_ + 4096); \
} while (0)

#define LDA_(buf, kk, mi) (*(const short8*)(As + (buf) * 16384 + (kk) * 8192 \
                           + (wm * 128 + (mi) * 16 + c15) * 32 + swz))
#define LDB_(buf, kk, nj) (*(const short8*)(Bs + (buf) * 16384 + (kk) * 8192 \
                           + (wn * 64 + (nj) * 16 + c15) * 32 + swz))

#define MFMA4x4(MB) do { \
    __builtin_amdgcn_s_setprio(1); \
    _Pragma("unroll") \
    for (int mi_ = 0; mi_ < 4; ++mi_) \
        _Pragma("unroll") \
        for (int nj_ = 0; nj_ < 4; ++nj_) \
            acc[(MB) + mi_][nj_] = __builtin_amdgcn_mfma_f32_16x16x32_bf16( \
                af[mi_], bf4[nj_], acc[(MB) + mi_][nj_], 0, 0, 0); \
    __builtin_amdgcn_s_setprio(0); \
} while (0)

    f32x4 acc[8][4];
    #pragma unroll
    for (int i = 0; i < 8; ++i)
        #pragma unroll
        for (int j = 0; j < 4; ++j)
            acc[i][j] = (f32x4){0.f, 0.f, 0.f, 0.f};

    STG_A(0, 0, 0); STG_B(0, 0, 0); STG_A(0, 1, 0); STG_B(0, 1, 0);
    WAITV(4); SBAR(); SCHED0();

    for (int t = 0; t < Ktiles; ++t) {
        const int c = t & 1, nb = c ^ 1;
        const bool st = (t + 1 < Ktiles);
        const int u = t + 1;
        short8 af[4], bf4[4];

        #pragma unroll
        for (int mi = 0; mi < 4; ++mi) af[mi] = LDA_(c, 0, mi);
        #pragma unroll
        for (int nj = 0; nj < 4; ++nj) bf4[nj] = LDB_(c, 0, nj);
        if (st) STG_A(u, 0, nb);
        SBAR();
        MFMA4x4(0);
        SBAR();

        #pragma unroll
        for (int mi = 0; mi < 4; ++mi) af[mi] = LDA_(c, 0, 4 + mi);
        if (st) STG_B(u, 0, nb);
        if (st) { WAITV(4); } else { WAITV(0); }
        SBAR(); SCHED0();
        MFMA4x4(4);
        SBAR();

        #pragma unroll
        for (int mi = 0; mi < 4; ++mi) af[mi] = LDA_(c, 1, mi);
        #pragma unroll
        for (int nj = 0; nj < 4; ++nj) bf4[nj] = LDB_(c, 1, nj);
        if (st) STG_A(u, 1, nb);
        SBAR();
        MFMA4x4(0);
        SBAR();

        #pragma unroll
        for (int mi = 0; mi < 4; ++mi) af[mi] = LDA_(c, 1, 4 + mi);
        if (st) STG_B(u, 1, nb);
        if (st) { WAITV(4); } else { WAITV(0); }
        SBAR(); SCHED0();
        MFMA4x4(4);
        SBAR();
    }

    float bv[4];
    #pragma unroll
    for (int nj = 0; nj < 4; ++nj)
        bv[nj] = bias ? bias[n0 + wn * 64 + nj * 16 + c15] : 0.f;
    #pragma unroll
    for (int mi = 0; mi < 8; ++mi) {
        #pragma unroll
        for (int r = 0; r < 4; ++r) {
            const size_t row = (size_t)m0 + wm * 128 + mi * 16 + g4 + r;
            #pragma unroll
            for (int nj = 0; nj < 4; ++nj) {
                const int col = n0 + wn * 64 + nj * 16 + c15;
                const float v = acc[mi][nj][r] + bv[nj];
                if (F32OUT) ((float*)Cout)[row * (size_t)ldc + col] = v;
                else        ((short*)Cout)[row * (size_t)ldc + col] = f2bf(v);
            }
        }
    }
#undef STG_A
#undef STG_B
#undef LDA_
#undef LDB_
#undef MFMA4x4
}

// ---------------------------------------------------------------------------
// Per (head, block) causal attention. qkvh: [16384][3072] bf16, q at cols
// 0-1023, k at +1024, v at +2048 (col within each = h*64+e). obuf [16384][1024].
// ---------------------------------------------------------------------------
__global__ __launch_bounds__(256) void attn_kernel(
    const short* __restrict__ qkvh, short* __restrict__ obuf)
{
    __shared__ __align__(16) char smem[54272];
    short* qs = (short*)smem;                 // [128][72]
    short* ks = (short*)smem + 9216;          // [128][72]
    short* vt = (short*)(smem + 36864);       // [64][136]  (v transposed)
    short* ps = (short*)smem;                 // [128][136] (reuses qs+ks region)
    short* os = (short*)smem;                 // [128][72]  (reused post-PV)

    const int tid = threadIdx.x, lane = tid & 63, wid = tid >> 6;
    const int h = blockIdx.x, b = blockIdx.y;
    const size_t base = (size_t)b * 128 * 3072 + (size_t)h * 64;

    for (int i = tid; i < 1024; i += 256) {
        const int row = i >> 3, c8 = i & 7;
        const size_t g = base + (size_t)row * 3072 + c8 * 8;
        *(short8*)(qs + row * 72 + c8 * 8) = *(const short8*)(qkvh + g);
        *(short8*)(ks + row * 72 + c8 * 8) = *(const short8*)(qkvh + g + 1024);
        short8 vv = *(const short8*)(qkvh + g + 2048);
        #pragma unroll
        for (int j = 0; j < 8; ++j) vt[(c8 * 8 + j) * 136 + row] = vv[j];
    }
    __syncthreads();

    const int c15 = lane & 15, g8 = (lane >> 4) * 8, g4 = (lane >> 4) * 4;
    const int r0 = wid * 32;

    f32x4 sacc[2][8];
    #pragma unroll
    for (int mi = 0; mi < 2; ++mi)
        #pragma unroll
        for (int nj = 0; nj < 8; ++nj)
            sacc[mi][nj] = (f32x4){0.f, 0.f, 0.f, 0.f};
    #pragma unroll
    for (int kk = 0; kk < 2; ++kk) {
        short8 aq[2];
        #pragma unroll
        for (int mi = 0; mi < 2; ++mi)
            aq[mi] = *(const short8*)(qs + (r0 + mi * 16 + c15) * 72 + kk * 32 + g8);
        #pragma unroll
        for (int nj = 0; nj < 8; ++nj) {
            short8 bk8 = *(const short8*)(ks + (nj * 16 + c15) * 72 + kk * 32 + g8);
            #pragma unroll
            for (int mi = 0; mi < 2; ++mi)
                sacc[mi][nj] = __builtin_amdgcn_mfma_f32_16x16x32_bf16(
                    aq[mi], bk8, sacc[mi][nj], 0, 0, 0);
        }
    }
    __syncthreads();

    #pragma unroll
    for (int mi = 0; mi < 2; ++mi) {
        #pragma unroll
        for (int r = 0; r < 4; ++r) {
            const int qrow = r0 + mi * 16 + g4 + r;
            float m = -3.0e38f, pv[8];
            #pragma unroll
            for (int nj = 0; nj < 8; ++nj) {
                float s = sacc[mi][nj][r] * 0.125f;
                if (nj * 16 + c15 > qrow) s = -1.0e9f;
                pv[nj] = s; m = fmaxf(m, s);
            }
            #pragma unroll
            for (int off = 8; off >= 1; off >>= 1) m = fmaxf(m, __shfl_xor(m, off));
            float sum = 0.f;
            #pragma unroll
            for (int nj = 0; nj < 8; ++nj) { float p = __expf(pv[nj] - m); pv[nj] = p; sum += p; }
            #pragma unroll
            for (int off = 8; off >= 1; off >>= 1) sum += __shfl_xor(sum, off);
            const float inv = 1.0f / sum;
            #pragma unroll
            for (int nj = 0; nj < 8; ++nj)
                ps[qrow * 136 + nj * 16 + c15] = f2bf(pv[nj] * inv);
        }
    }
    __syncthreads();

    f32x4 oacc[2][4];
    #pragma unroll
    for (int mi = 0; mi < 2; ++mi)
        #pragma unroll
        for (int nj = 0; nj < 4; ++nj)
            oacc[mi][nj] = (f32x4){0.f, 0.f, 0.f, 0.f};
    #pragma unroll
    for (int kt = 0; kt < 4; ++kt) {
        short8 ap[2];
        #pragma unroll
        for (int mi = 0; mi < 2; ++mi)
            ap[mi] = *(const short8*)(ps + (r0 + mi * 16 + c15) * 136 + kt * 32 + g8);
        #pragma unroll
        for (int nj = 0; nj < 4; ++nj) {
            short8 bv8 = *(const short8*)(vt + (nj * 16 + c15) * 136 + kt * 32 + g8);
            #pragma unroll
            for (int mi = 0; mi < 2; ++mi)
                oacc[mi][nj] = __builtin_amdgcn_mfma_f32_16x16x32_bf16(
                    ap[mi], bv8, oacc[mi][nj], 0, 0, 0);
        }
    }
    __syncthreads();

    #pragma unroll
    for (int mi = 0; mi < 2; ++mi)
        #pragma unroll
        for (int r = 0; r < 4; ++r)
            #pragma unroll
            for (int nj = 0; nj < 4; ++nj)
                os[(r0 + mi * 16 + g4 + r) * 72 + nj * 16 + c15] = f2bf(oacc[mi][nj][r]);
    __syncthreads();

    for (int i = tid; i < 1024; i += 256) {
        const int row = i >> 3, c8 = i & 7;
        *(short8*)(obuf + (size_t)b * 128 * 1024 + (size_t)h * 64
                   + (size_t)row * 1024 + c8 * 8) =
            *(const short8*)(os + row * 72 + c8 * 8);
    }
}

// ---------------------------------------------------------------------------
__global__ void pad_convert_inputs(const float* __restrict__ in, short* __restrict__ out)
{
    const int row = blockIdx.x;                 // [0, 16388)
    const int n = row / 8194, l = row % 8194;
    short* orow = out + (size_t)row * 4096;
    if (l == 0 || l == 8193) {
        for (int i = threadIdx.x; i < 512; i += 256) {
            uint4 z; z.x = z.y = z.z = z.w = 0u;
            *(uint4*)(orow + i * 8) = z;
        }
    } else {
        const float* irow = in + ((size_t)n * 8192 + (l - 1)) * 4096;
        for (int i = threadIdx.x; i < 512; i += 256) {
            float4 a = *(const float4*)(irow + i * 8);
            float4 b = *(const float4*)(irow + i * 8 + 4);
            short8 v;
            v[0] = f2bf(a.x); v[1] = f2bf(a.y); v[2] = f2bf(a.z); v[3] = f2bf(a.w);
            v[4] = f2bf(b.x); v[5] = f2bf(b.y); v[6] = f2bf(b.z); v[7] = f2bf(b.w);
            *(short8*)(orow + i * 8) = v;
        }
    }
}

__global__ void transpose_convert(const float* __restrict__ in, short* __restrict__ out,
                                  int R, int C)
{
    __shared__ float tile[32][33];
    const int tx = threadIdx.x & 31, ty = threadIdx.x >> 5;   // 32 x 8
    const int bx = blockIdx.x * 32, by = blockIdx.y * 32;
    #pragma unroll
    for (int i = 0; i < 32; i += 8)
        tile[ty + i][tx] = in[(size_t)(by + ty + i) * C + bx + tx];
    __syncthreads();
    #pragma unroll
    for (int i = 0; i < 32; i += 8)
        out[(size_t)(bx + ty + i) * R + by + tx] = f2bf(tile[tx][ty + i]);
}

__global__ void convert_bf16(const float* __restrict__ in, short* __restrict__ out, int n8)
{
    const int idx = blockIdx.x * 256 + threadIdx.x;
    if (idx < n8) {
        float4 a = *(const float4*)(in + (size_t)idx * 8);
        float4 b = *(const float4*)(in + (size_t)idx * 8 + 4);
        short8 v;
        v[0] = f2bf(a.x); v[1] = f2bf(a.y); v[2] = f2bf(a.z); v[3] = f2bf(a.w);
        v[4] = f2bf(b.x); v[5] = f2bf(b.y); v[6] = f2bf(b.z); v[7] = f2bf(b.w);
        *(short8*)(out + (size_t)idx * 8) = v;
    }
}

__global__ void fuse_bias(const float* __restrict__ bo, const float* __restrict__ projw,
                          const float* __restrict__ projb, float* __restrict__ outb)
{
    const int j = blockIdx.x * 256 + threadIdx.x;   // 4096
    float s = projb[j];
    for (int w = 0; w < 1024; ++w) s = fmaf(bo[w], projw[(size_t)w * 4096 + j], s);
    outb[j] = s;
}

// b2[o] = b_part[o&1023] + sum_d conv_b[(o>>10)*1024+d] * wpart[d][o&1023]
__global__ void fuse_bias_qkv(const float* __restrict__ conv_b,
                              const float* __restrict__ wq, const float* __restrict__ bq,
                              const float* __restrict__ wk, const float* __restrict__ bk,
                              const float* __restrict__ wv, const float* __restrict__ bv,
                              float* __restrict__ outb)
{
    const int o = blockIdx.x * 256 + threadIdx.x;   // 3072
    const int p = o >> 10, e = o & 1023;
    const float* w = (p == 0) ? wq : (p == 1) ? wk : wv;
    const float* bb = (p == 0) ? bq : (p == 1) ? bk : bv;
    const float* cb = conv_b + p * 1024;
    float s = bb[e];
    for (int d = 0; d < 1024; ++d) s = fmaf(cb[d], w[(size_t)d * 1024 + e], s);
    outb[o] = s;
}

// ---------------------------------------------------------------------------
extern "C" void kernel_launch(void* const* d_in, const int* in_sizes, int n_in,
                              void* d_out, int out_size, void* d_ws, size_t ws_size,
                              hipStream_t stream)
{
    const float* inputs = (const float*)d_in[0];
    const float* conv_w = (const float*)d_in[1];
    const float* conv_b = (const float*)d_in[2];
    const float* wq     = (const float*)d_in[3];
    const float* bq     = (const float*)d_in[4];
    const float* wk     = (const float*)d_in[5];
    const float* bk     = (const float*)d_in[6];
    const float* wv     = (const float*)d_in[7];
    const float* bv     = (const float*)d_in[8];
    const float* wo     = (const float*)d_in[9];
    const float* bo     = (const float*)d_in[10];
    const float* proj_w = (const float*)d_in[11];
    const float* proj_b = (const float*)d_in[12];

    char* ws = (char*)d_ws;
    short* in_pad = (short*)(ws + 0);             // [2][8194][4096]      134,283,264 B
    short* cw_bf  = (short*)(ws + 134283264);     // [3][4096][3072] bf16 (dead after prep)
    short* qkvh   = (short*)(ws + 134283264);     // [16384][3072] over cw_bf
    short* W2T    = (short*)(ws + 234946560);     // [3][3072][4096] bf16
    short* wq_t   = (short*)(ws + 310444032);     // [3][1024][1024] BT contiguous
    short* wo_bf  = (short*)(ws + 316735488);     // [1024][1024]
    short* proj_t = (short*)(ws + 318832640);     // [4096][1024]
    short* WfT    = (short*)(ws + 327221248);     // [4096][1024]
    float* bfused = (float*)(ws + 335609856);     // [4096]
    float* b2     = (float*)(ws + 335626240);     // [3072]
    short* o_buf  = (short*)(ws + 0);             // [16384][1024] over in_pad

    dim3 blk(256), blk5(512);

    pad_convert_inputs<<<16388, blk, 0, stream>>>(inputs, in_pad);
    convert_bf16<<<18432, blk, 0, stream>>>(conv_w, cw_bf, 4718592);   // straight convert
    transpose_convert<<<dim3(32, 32), blk, 0, stream>>>(wq, wq_t, 1024, 1024);
    transpose_convert<<<dim3(32, 32), blk, 0, stream>>>(wk, wq_t + 1048576, 1024, 1024);
    transpose_convert<<<dim3(32, 32), blk, 0, stream>>>(wv, wq_t + 2097152, 1024, 1024);
    transpose_convert<<<dim3(128, 32), blk, 0, stream>>>(proj_w, proj_t, 1024, 4096);
    convert_bf16<<<512, blk, 0, stream>>>(wo, wo_bf, 131072);
    fuse_bias<<<16, blk, 0, stream>>>(bo, proj_w, proj_b, bfused);
    fuse_bias_qkv<<<12, blk, 0, stream>>>(conv_b, wq, bq, wk, bk, wv, bv, b2);

    // WfT[dm][he] = sum_w proj_t[dm][w] * wo_flat[he][w]
    gemm256<0, false><<<dim3(4, 16), blk5, 0, stream>>>(
        proj_t, 1024, wo_bf, 1024, WfT, 1024, nullptr, 16);
    // weight prep: W2T[t][o][i] = sum_d wqkvT[o][d] * conv_w[t][i][(o>>10)*1024+d]
    for (int t = 0; t < 3; ++t)
        gemm256<1, false><<<dim3(16, 12), blk5, 0, stream>>>(
            wq_t, 1024, cw_bf + (size_t)t * 4096 * 3072, 3072,
            W2T + (size_t)t * 3072 * 4096, 4096, nullptr, 16);
    // fused conv+projection, tap-shared A, 3 blocks/CU -> qkvh [16384][3072]
    conv3_gemm<<<dim3(24, 64), blk, 0, stream>>>(in_pad, W2T, qkvh, b2);

    attn_kernel<<<dim3(16, 128), blk, 0, stream>>>(qkvh, o_buf);

    // out = o @ Wf + bfused   (f32 out)
    gemm256<0, true><<<dim3(16, 64), blk5, 0, stream>>>(
        o_buf, 1024, WfT, 1024, d_out, 4096, bfused, 16);
}

// Round 16
// 1489.526 us; speedup vs baseline: 1.5095x; 1.0033x over previous
//
#include <hip/hip_runtime.h>
#include <hip/hip_bf16.h>
#include <stdint.h>

typedef __attribute__((ext_vector_type(8))) short short8;
typedef __attribute__((ext_vector_type(4))) float f32x4;

#define AS1 __attribute__((address_space(1)))
#define AS3 __attribute__((address_space(3)))

__device__ __forceinline__ short f2bf(float x) {
    __hip_bfloat16 h = __float2bfloat16(x);
    union { __hip_bfloat16 h; short s; } u; u.h = h; return u.s;
}

__device__ __forceinline__ void gload_lds16(const short* g, short* l) {
    __builtin_amdgcn_global_load_lds((const AS1 void*)g, (AS3 void*)l, 16, 0, 0);
}

#define SBAR()   __builtin_amdgcn_s_barrier()
#define WAITV(N) asm volatile("s_waitcnt vmcnt(" #N ")")
#define SCHED0() __builtin_amdgcn_sched_barrier(0)

// ---------------------------------------------------------------------------
// conv3 (r15, confirmed 62% MfmaUtil): 3 blocks/CU, 256 threads (4 waves,
// 2wm x 2wn), tile 256x128, BK=32, single-buffered tap-shared A[258][32] +
// B[3][128][32] = 41 KB LDS. Cross-block MFMA/LDS overlap (m114) broke the
// 15-round 45-47% plateau. Step: {vmcnt0; bar; reads+MFMA(3 taps); bar;
// STAGE(s+1)}. Involutions as audited in r15 (0 conflicts measured).
// ---------------------------------------------------------------------------
__global__ __launch_bounds__(256, 3) void conv3_gemm(
    const short* __restrict__ A,        // in_pad [2*8194][4096]
    const short* __restrict__ BT,       // W2T [3][3072][4096]
    short* __restrict__ Cout,           // qkvh [16384][3072]
    const float* __restrict__ bias)     // b2 [3072]
{
    __shared__ __align__(16) short As[258 * 32];      // 16,512 B
    __shared__ __align__(16) short Bs[3 * 128 * 32];  // 24,576 B
    const int tid = threadIdx.x, lane = tid & 63, wid = tid >> 6;
    const int wm = wid >> 1, wn = wid & 1;
    const int m0 = blockIdx.y * 256, n0 = blockIdx.x * 128;
    const size_t arow0 = (size_t)(m0 >> 13) * 8194 + (size_t)(m0 & 8191);
    const short* Abase = A + arow0 * 4096;
    const short* Bbase = BT + (size_t)n0 * 4096;
    const int c15 = lane & 15, g = lane >> 4, g4 = g * 4;
    const int xr0 = (c15 >> 1) & 3;
    const int xr1 = ((c15 + 1) >> 1) & 3;
    const int xr2 = ((c15 + 2) >> 1) & 3;
    const int srow = tid >> 2;
    const int schunk = (((tid & 3) ^ ((tid >> 3) & 3)) * 8);
    const int srowB = wid * 32 + (lane >> 2);
    const int schunkB = (((lane & 3) ^ ((lane >> 3) & 3)) * 8);

#define STAGE(s) do { \
    const int kc_ = (s) * 32; \
    const short* ga_ = Abase + (size_t)srow * 4096 + kc_ + schunk; \
    short* la_ = As + wid * 512; \
    gload_lds16(ga_, la_); \
    gload_lds16(ga_ + (size_t)64 * 4096, la_ + 2048); \
    gload_lds16(ga_ + (size_t)128 * 4096, la_ + 4096); \
    gload_lds16(ga_ + (size_t)192 * 4096, la_ + 6144); \
    if (wid == 3 && lane < 8) \
        gload_lds16(Abase + (size_t)(256 + (lane >> 2)) * 4096 + kc_ + (lane & 3) * 8, \
                    As + 8192); \
    _Pragma("unroll") \
    for (int tp_ = 0; tp_ < 3; ++tp_) { \
        const short* gb_ = Bbase + (size_t)tp_ * 3072 * 4096 \
                           + (size_t)srowB * 4096 + kc_ + schunkB; \
        short* lb_ = Bs + tp_ * 4096 + wid * 1024; \
        gload_lds16(gb_, lb_); \
        gload_lds16(gb_ + (size_t)16 * 4096, lb_ + 512); \
    } \
} while (0)

#define LDA_T(mi, T, XR) (*(const short8*)(As \
    + (wm * 128 + (mi) * 16 + c15 + (T)) * 32 + ((g ^ (XR)) * 8)))
#define LDB_T(tp, nj) (*(const short8*)(Bs + (tp) * 4096 \
    + (wn * 64 + (nj) * 16 + c15) * 32 + ((g ^ xr0) * 8)))

    f32x4 acc[8][4];
    #pragma unroll
    for (int i = 0; i < 8; ++i)
        #pragma unroll
        for (int j = 0; j < 4; ++j)
            acc[i][j] = (f32x4){0.f, 0.f, 0.f, 0.f};

    STAGE(0);

    for (int s = 0; s < 128; ++s) {
        WAITV(0); SBAR(); SCHED0();
        #pragma unroll
        for (int tp = 0; tp < 3; ++tp) {
            const int xr = (tp == 0) ? xr0 : (tp == 1) ? xr1 : xr2;
            short8 b0 = LDB_T(tp, 0), b1 = LDB_T(tp, 1);
            short8 b2f = LDB_T(tp, 2), b3 = LDB_T(tp, 3);
            __builtin_amdgcn_s_setprio(1);
            #pragma unroll
            for (int mi = 0; mi < 8; ++mi) {
                short8 a = LDA_T(mi, tp, xr);
                acc[mi][0] = __builtin_amdgcn_mfma_f32_16x16x32_bf16(a, b0, acc[mi][0], 0, 0, 0);
                acc[mi][1] = __builtin_amdgcn_mfma_f32_16x16x32_bf16(a, b1, acc[mi][1], 0, 0, 0);
                acc[mi][2] = __builtin_amdgcn_mfma_f32_16x16x32_bf16(a, b2f, acc[mi][2], 0, 0, 0);
                acc[mi][3] = __builtin_amdgcn_mfma_f32_16x16x32_bf16(a, b3, acc[mi][3], 0, 0, 0);
            }
            __builtin_amdgcn_s_setprio(0);
        }
        SBAR();
        if (s + 1 < 128) STAGE(s + 1);
    }

    float bv[4];
    #pragma unroll
    for (int nj = 0; nj < 4; ++nj)
        bv[nj] = bias[n0 + wn * 64 + nj * 16 + c15];
    #pragma unroll
    for (int mi = 0; mi < 8; ++mi) {
        #pragma unroll
        for (int r = 0; r < 4; ++r) {
            const size_t row = (size_t)m0 + wm * 128 + mi * 16 + g4 + r;
            #pragma unroll
            for (int nj = 0; nj < 4; ++nj) {
                const int col = n0 + wn * 64 + nj * 16 + c15;
                Cout[row * 3072 + col] = f2bf(acc[mi][nj][r] + bv[nj]);
            }
        }
    }
#undef STAGE
#undef LDA_T
#undef LDB_T
}

// ---------------------------------------------------------------------------
// gemm128 (r16): the r15 winning structure applied to plain GEMMs.
// 256 threads (4 waves, 2wm x 2wn), tile 256x128, BK=32, single-buffered
// A[256][32] + B[128][32] = 24 KB LDS -> 3+ blocks/CU. Same step schedule
// and staging/read involutions as conv3 (B-row XOR: (lane>>3)&3; wid*32
// is a multiple of 8 so it drops out of (row>>1)&3).
// MODE: 0 = plain; 1 = QKVB (weight-prep: B col base += m0 & ~1023).
// ---------------------------------------------------------------------------
template<int MODE, bool F32OUT>
__global__ __launch_bounds__(256, 3) void gemm128(
    const short* __restrict__ A, int lda,
    const short* __restrict__ BT, int ldb,
    void* __restrict__ Cout, int ldc,
    const float* __restrict__ bias, int Ksteps)
{
    __shared__ __align__(16) short As[256 * 32];   // 16 KB
    __shared__ __align__(16) short Bs[128 * 32];   //  8 KB
    const int tid = threadIdx.x, lane = tid & 63, wid = tid >> 6;
    const int wm = wid >> 1, wn = wid & 1;
    const int m0 = blockIdx.y * 256, n0 = blockIdx.x * 128;
    const size_t ldaS = (size_t)lda, ldbS = (size_t)ldb;
    const short* Abase = A + (size_t)m0 * ldaS;
    const short* Bbase = BT + (size_t)n0 * ldbS + ((MODE == 1) ? (m0 & ~1023) : 0);
    const int c15 = lane & 15, g = lane >> 4, g4 = g * 4;
    const int xr0 = (c15 >> 1) & 3;
    const int srow = tid >> 2;
    const int schunk = (((tid & 3) ^ ((tid >> 3) & 3)) * 8);
    const int srowB = wid * 32 + (lane >> 2);
    const int schunkB = (((lane & 3) ^ ((lane >> 3) & 3)) * 8);

#define STG(s) do { \
    const int kc_ = (s) * 32; \
    const short* ga_ = Abase + (size_t)srow * ldaS + kc_ + schunk; \
    short* la_ = As + wid * 512; \
    gload_lds16(ga_, la_); \
    gload_lds16(ga_ + (size_t)64 * ldaS, la_ + 2048); \
    gload_lds16(ga_ + (size_t)128 * ldaS, la_ + 4096); \
    gload_lds16(ga_ + (size_t)192 * ldaS, la_ + 6144); \
    const short* gb_ = Bbase + (size_t)srowB * ldbS + kc_ + schunkB; \
    short* lb_ = Bs + wid * 1024; \
    gload_lds16(gb_, lb_); \
    gload_lds16(gb_ + (size_t)16 * ldbS, lb_ + 512); \
} while (0)

#define LDA_(mi) (*(const short8*)(As + (wm * 128 + (mi) * 16 + c15) * 32 + ((g ^ xr0) * 8)))
#define LDB_(nj) (*(const short8*)(Bs + (wn * 64 + (nj) * 16 + c15) * 32 + ((g ^ xr0) * 8)))

    f32x4 acc[8][4];
    #pragma unroll
    for (int i = 0; i < 8; ++i)
        #pragma unroll
        for (int j = 0; j < 4; ++j)
            acc[i][j] = (f32x4){0.f, 0.f, 0.f, 0.f};

    STG(0);

    for (int s = 0; s < Ksteps; ++s) {
        WAITV(0); SBAR(); SCHED0();
        short8 b0 = LDB_(0), b1 = LDB_(1), b2f = LDB_(2), b3 = LDB_(3);
        __builtin_amdgcn_s_setprio(1);
        #pragma unroll
        for (int mi = 0; mi < 8; ++mi) {
            short8 a = LDA_(mi);
            acc[mi][0] = __builtin_amdgcn_mfma_f32_16x16x32_bf16(a, b0, acc[mi][0], 0, 0, 0);
            acc[mi][1] = __builtin_amdgcn_mfma_f32_16x16x32_bf16(a, b1, acc[mi][1], 0, 0, 0);
            acc[mi][2] = __builtin_amdgcn_mfma_f32_16x16x32_bf16(a, b2f, acc[mi][2], 0, 0, 0);
            acc[mi][3] = __builtin_amdgcn_mfma_f32_16x16x32_bf16(a, b3, acc[mi][3], 0, 0, 0);
        }
        __builtin_amdgcn_s_setprio(0);
        SBAR();
        if (s + 1 < Ksteps) STG(s + 1);
    }

    float bv[4];
    #pragma unroll
    for (int nj = 0; nj < 4; ++nj)
        bv[nj] = bias ? bias[n0 + wn * 64 + nj * 16 + c15] : 0.f;
    #pragma unroll
    for (int mi = 0; mi < 8; ++mi) {
        #pragma unroll
        for (int r = 0; r < 4; ++r) {
            const size_t row = (size_t)m0 + wm * 128 + mi * 16 + g4 + r;
            #pragma unroll
            for (int nj = 0; nj < 4; ++nj) {
                const int col = n0 + wn * 64 + nj * 16 + c15;
                const float v = acc[mi][nj][r] + bv[nj];
                if (F32OUT) ((float*)Cout)[row * (size_t)ldc + col] = v;
                else        ((short*)Cout)[row * (size_t)ldc + col] = f2bf(v);
            }
        }
    }
#undef STG
#undef LDA_
#undef LDB_
}

// ---------------------------------------------------------------------------
// Per (head, block) causal attention. qkvh: [16384][3072] bf16, q at cols
// 0-1023, k at +1024, v at +2048 (col within each = h*64+e). obuf [16384][1024].
// ---------------------------------------------------------------------------
__global__ __launch_bounds__(256) void attn_kernel(
    const short* __restrict__ qkvh, short* __restrict__ obuf)
{
    __shared__ __align__(16) char smem[54272];
    short* qs = (short*)smem;                 // [128][72]
    short* ks = (short*)smem + 9216;          // [128][72]
    short* vt = (short*)(smem + 36864);       // [64][136]  (v transposed)
    short* ps = (short*)smem;                 // [128][136] (reuses qs+ks region)
    short* os = (short*)smem;                 // [128][72]  (reused post-PV)

    const int tid = threadIdx.x, lane = tid & 63, wid = tid >> 6;
    const int h = blockIdx.x, b = blockIdx.y;
    const size_t base = (size_t)b * 128 * 3072 + (size_t)h * 64;

    for (int i = tid; i < 1024; i += 256) {
        const int row = i >> 3, c8 = i & 7;
        const size_t g = base + (size_t)row * 3072 + c8 * 8;
        *(short8*)(qs + row * 72 + c8 * 8) = *(const short8*)(qkvh + g);
        *(short8*)(ks + row * 72 + c8 * 8) = *(const short8*)(qkvh + g + 1024);
        short8 vv = *(const short8*)(qkvh + g + 2048);
        #pragma unroll
        for (int j = 0; j < 8; ++j) vt[(c8 * 8 + j) * 136 + row] = vv[j];
    }
    __syncthreads();

    const int c15 = lane & 15, g8 = (lane >> 4) * 8, g4 = (lane >> 4) * 4;
    const int r0 = wid * 32;

    f32x4 sacc[2][8];
    #pragma unroll
    for (int mi = 0; mi < 2; ++mi)
        #pragma unroll
        for (int nj = 0; nj < 8; ++nj)
            sacc[mi][nj] = (f32x4){0.f, 0.f, 0.f, 0.f};
    #pragma unroll
    for (int kk = 0; kk < 2; ++kk) {
        short8 aq[2];
        #pragma unroll
        for (int mi = 0; mi < 2; ++mi)
            aq[mi] = *(const short8*)(qs + (r0 + mi * 16 + c15) * 72 + kk * 32 + g8);
        #pragma unroll
        for (int nj = 0; nj < 8; ++nj) {
            short8 bk8 = *(const short8*)(ks + (nj * 16 + c15) * 72 + kk * 32 + g8);
            #pragma unroll
            for (int mi = 0; mi < 2; ++mi)
                sacc[mi][nj] = __builtin_amdgcn_mfma_f32_16x16x32_bf16(
                    aq[mi], bk8, sacc[mi][nj], 0, 0, 0);
        }
    }
    __syncthreads();

    #pragma unroll
    for (int mi = 0; mi < 2; ++mi) {
        #pragma unroll
        for (int r = 0; r < 4; ++r) {
            const int qrow = r0 + mi * 16 + g4 + r;
            float m = -3.0e38f, pv[8];
            #pragma unroll
            for (int nj = 0; nj < 8; ++nj) {
                float s = sacc[mi][nj][r] * 0.125f;
                if (nj * 16 + c15 > qrow) s = -1.0e9f;
                pv[nj] = s; m = fmaxf(m, s);
            }
            #pragma unroll
            for (int off = 8; off >= 1; off >>= 1) m = fmaxf(m, __shfl_xor(m, off));
            float sum = 0.f;
            #pragma unroll
            for (int nj = 0; nj < 8; ++nj) { float p = __expf(pv[nj] - m); pv[nj] = p; sum += p; }
            #pragma unroll
            for (int off = 8; off >= 1; off >>= 1) sum += __shfl_xor(sum, off);
            const float inv = 1.0f / sum;
            #pragma unroll
            for (int nj = 0; nj < 8; ++nj)
                ps[qrow * 136 + nj * 16 + c15] = f2bf(pv[nj] * inv);
        }
    }
    __syncthreads();

    f32x4 oacc[2][4];
    #pragma unroll
    for (int mi = 0; mi < 2; ++mi)
        #pragma unroll
        for (int nj = 0; nj < 4; ++nj)
            oacc[mi][nj] = (f32x4){0.f, 0.f, 0.f, 0.f};
    #pragma unroll
    for (int kt = 0; kt < 4; ++kt) {
        short8 ap[2];
        #pragma unroll
        for (int mi = 0; mi < 2; ++mi)
            ap[mi] = *(const short8*)(ps + (r0 + mi * 16 + c15) * 136 + kt * 32 + g8);
        #pragma unroll
        for (int nj = 0; nj < 4; ++nj) {
            short8 bv8 = *(const short8*)(vt + (nj * 16 + c15) * 136 + kt * 32 + g8);
            #pragma unroll
            for (int mi = 0; mi < 2; ++mi)
                oacc[mi][nj] = __builtin_amdgcn_mfma_f32_16x16x32_bf16(
                    ap[mi], bv8, oacc[mi][nj], 0, 0, 0);
        }
    }
    __syncthreads();

    #pragma unroll
    for (int mi = 0; mi < 2; ++mi)
        #pragma unroll
        for (int r = 0; r < 4; ++r)
            #pragma unroll
            for (int nj = 0; nj < 4; ++nj)
                os[(r0 + mi * 16 + g4 + r) * 72 + nj * 16 + c15] = f2bf(oacc[mi][nj][r]);
    __syncthreads();

    for (int i = tid; i < 1024; i += 256) {
        const int row = i >> 3, c8 = i & 7;
        *(short8*)(obuf + (size_t)b * 128 * 1024 + (size_t)h * 64
                   + (size_t)row * 1024 + c8 * 8) =
            *(const short8*)(os + row * 72 + c8 * 8);
    }
}

// ---------------------------------------------------------------------------
__global__ void pad_convert_inputs(const float* __restrict__ in, short* __restrict__ out)
{
    const int row = blockIdx.x;                 // [0, 16388)
    const int n = row / 8194, l = row % 8194;
    short* orow = out + (size_t)row * 4096;
    if (l == 0 || l == 8193) {
        for (int i = threadIdx.x; i < 512; i += 256) {
            uint4 z; z.x = z.y = z.z = z.w = 0u;
            *(uint4*)(orow + i * 8) = z;
        }
    } else {
        const float* irow = in + ((size_t)n * 8192 + (l - 1)) * 4096;
        for (int i = threadIdx.x; i < 512; i += 256) {
            float4 a = *(const float4*)(irow + i * 8);
            float4 b = *(const float4*)(irow + i * 8 + 4);
            short8 v;
            v[0] = f2bf(a.x); v[1] = f2bf(a.y); v[2] = f2bf(a.z); v[3] = f2bf(a.w);
            v[4] = f2bf(b.x); v[5] = f2bf(b.y); v[6] = f2bf(b.z); v[7] = f2bf(b.w);
            *(short8*)(orow + i * 8) = v;
        }
    }
}

__global__ void transpose_convert(const float* __restrict__ in, short* __restrict__ out,
                                  int R, int C)
{
    __shared__ float tile[32][33];
    const int tx = threadIdx.x & 31, ty = threadIdx.x >> 5;   // 32 x 8
    const int bx = blockIdx.x * 32, by = blockIdx.y * 32;
    #pragma unroll
    for (int i = 0; i < 32; i += 8)
        tile[ty + i][tx] = in[(size_t)(by + ty + i) * C + bx + tx];
    __syncthreads();
    #pragma unroll
    for (int i = 0; i < 32; i += 8)
        out[(size_t)(bx + ty + i) * R + by + tx] = f2bf(tile[tx][ty + i]);
}

__global__ void convert_bf16(const float* __restrict__ in, short* __restrict__ out, int n8)
{
    const int idx = blockIdx.x * 256 + threadIdx.x;
    if (idx < n8) {
        float4 a = *(const float4*)(in + (size_t)idx * 8);
        float4 b = *(const float4*)(in + (size_t)idx * 8 + 4);
        short8 v;
        v[0] = f2bf(a.x); v[1] = f2bf(a.y); v[2] = f2bf(a.z); v[3] = f2bf(a.w);
        v[4] = f2bf(b.x); v[5] = f2bf(b.y); v[6] = f2bf(b.z); v[7] = f2bf(b.w);
        *(short8*)(out + (size_t)idx * 8) = v;
    }
}

__global__ void fuse_bias(const float* __restrict__ bo, const float* __restrict__ projw,
                          const float* __restrict__ projb, float* __restrict__ outb)
{
    const int j = blockIdx.x * 256 + threadIdx.x;   // 4096
    float s = projb[j];
    for (int w = 0; w < 1024; ++w) s = fmaf(bo[w], projw[(size_t)w * 4096 + j], s);
    outb[j] = s;
}

// b2[o] = b_part[o&1023] + sum_d conv_b[(o>>10)*1024+d] * wpart[d][o&1023]
__global__ void fuse_bias_qkv(const float* __restrict__ conv_b,
                              const float* __restrict__ wq, const float* __restrict__ bq,
                              const float* __restrict__ wk, const float* __restrict__ bk,
                              const float* __restrict__ wv, const float* __restrict__ bv,
                              float* __restrict__ outb)
{
    const int o = blockIdx.x * 256 + threadIdx.x;   // 3072
    const int p = o >> 10, e = o & 1023;
    const float* w = (p == 0) ? wq : (p == 1) ? wk : wv;
    const float* bb = (p == 0) ? bq : (p == 1) ? bk : bv;
    const float* cb = conv_b + p * 1024;
    float s = bb[e];
    for (int d = 0; d < 1024; ++d) s = fmaf(cb[d], w[(size_t)d * 1024 + e], s);
    outb[o] = s;
}

// ---------------------------------------------------------------------------
extern "C" void kernel_launch(void* const* d_in, const int* in_sizes, int n_in,
                              void* d_out, int out_size, void* d_ws, size_t ws_size,
                              hipStream_t stream)
{
    const float* inputs = (const float*)d_in[0];
    const float* conv_w = (const float*)d_in[1];
    const float* conv_b = (const float*)d_in[2];
    const float* wq     = (const float*)d_in[3];
    const float* bq     = (const float*)d_in[4];
    const float* wk     = (const float*)d_in[5];
    const float* bk     = (const float*)d_in[6];
    const float* wv     = (const float*)d_in[7];
    const float* bv     = (const float*)d_in[8];
    const float* wo     = (const float*)d_in[9];
    const float* bo     = (const float*)d_in[10];
    const float* proj_w = (const float*)d_in[11];
    const float* proj_b = (const float*)d_in[12];

    char* ws = (char*)d_ws;
    short* in_pad = (short*)(ws + 0);             // [2][8194][4096]      134,283,264 B
    short* cw_bf  = (short*)(ws + 134283264);     // [3][4096][3072] bf16 (dead after prep)
    short* qkvh   = (short*)(ws + 134283264);     // [16384][3072] over cw_bf
    short* W2T    = (short*)(ws + 234946560);     // [3][3072][4096] bf16
    short* wq_t   = (short*)(ws + 310444032);     // [3][1024][1024] BT contiguous
    short* wo_bf  = (short*)(ws + 316735488);     // [1024][1024]
    short* proj_t = (short*)(ws + 318832640);     // [4096][1024]
    short* WfT    = (short*)(ws + 327221248);     // [4096][1024]
    float* bfused = (float*)(ws + 335609856);     // [4096]
    float* b2     = (float*)(ws + 335626240);     // [3072]
    short* o_buf  = (short*)(ws + 0);             // [16384][1024] over in_pad

    dim3 blk(256);

    pad_convert_inputs<<<16388, blk, 0, stream>>>(inputs, in_pad);
    convert_bf16<<<18432, blk, 0, stream>>>(conv_w, cw_bf, 4718592);   // straight convert
    transpose_convert<<<dim3(32, 32), blk, 0, stream>>>(wq, wq_t, 1024, 1024);
    transpose_convert<<<dim3(32, 32), blk, 0, stream>>>(wk, wq_t + 1048576, 1024, 1024);
    transpose_convert<<<dim3(32, 32), blk, 0, stream>>>(wv, wq_t + 2097152, 1024, 1024);
    transpose_convert<<<dim3(128, 32), blk, 0, stream>>>(proj_w, proj_t, 1024, 4096);
    convert_bf16<<<512, blk, 0, stream>>>(wo, wo_bf, 131072);
    fuse_bias<<<16, blk, 0, stream>>>(bo, proj_w, proj_b, bfused);
    fuse_bias_qkv<<<12, blk, 0, stream>>>(conv_b, wq, bq, wk, bk, wv, bv, b2);

    // WfT[dm][he] = sum_w proj_t[dm][w] * wo_flat[he][w]
    gemm128<0, false><<<dim3(8, 16), blk, 0, stream>>>(
        proj_t, 1024, wo_bf, 1024, WfT, 1024, nullptr, 32);
    // weight prep: W2T[t][o][i] = sum_d wqkvT[o][d] * conv_w[t][i][(o>>10)*1024+d]
    for (int t = 0; t < 3; ++t)
        gemm128<1, false><<<dim3(32, 12), blk, 0, stream>>>(
            wq_t, 1024, cw_bf + (size_t)t * 4096 * 3072, 3072,
            W2T + (size_t)t * 3072 * 4096, 4096, nullptr, 32);
    // fused conv+projection, tap-shared A, 3 blocks/CU -> qkvh [16384][3072]
    conv3_gemm<<<dim3(24, 64), blk, 0, stream>>>(in_pad, W2T, qkvh, b2);

    attn_kernel<<<dim3(16, 128), blk, 0, stream>>>(qkvh, o_buf);

    // out = o @ Wf + bfused   (f32 out)
    gemm128<0, true><<<dim3(32, 64), blk, 0, stream>>>(
        o_buf, 1024, WfT, 1024, d_out, 4096, bfused, 32);
}